// Round 1
// baseline (650.793 us; speedup 1.0000x reference)
//
#include <hip/hip_runtime.h>

#define N_NODES 100000
#define N_EDGES 1600000
#define F_INPUT 256
#define H_DIM   128
#define C_DIM   40
#define NB1     ((N_NODES + 255) / 256)   // 391 scan blocks

typedef short  bf8   __attribute__((ext_vector_type(8)));
typedef float  f32x4 __attribute__((ext_vector_type(4)));

static __device__ __forceinline__ unsigned short f2bf(float f) {
    union { float f; unsigned u; } v; v.f = f;
    unsigned r = v.u + 0x7FFFu + ((v.u >> 16) & 1u);
    return (unsigned short)(r >> 16);
}
static __device__ __forceinline__ float bf2f(unsigned short b) {
    union { unsigned u; float f; } v; v.u = ((unsigned)b) << 16;
    return v.f;
}

// ---------- norm preprocessing ----------
__global__ void k_init(float* deg, int* count, int* cursor) {
    int i = blockIdx.x * 256 + threadIdx.x;
    if (i < N_NODES) { deg[i] = 1.0f; count[i] = 0; cursor[i] = 0; }
}

__global__ void k_count(const int* __restrict__ col, const float* __restrict__ ea,
                        float* deg, int* count) {
    int e = blockIdx.x * 256 + threadIdx.x;
    if (e < N_EDGES) {
        int c = col[e];
        atomicAdd(deg + c, ea[e]);
        atomicAdd(count + c, 1);
    }
}

__global__ void k_rsqrt(float* deg) {
    int i = blockIdx.x * 256 + threadIdx.x;
    if (i < N_NODES) deg[i] = rsqrtf(deg[i]);   // deg >= 1 always (self-loop)
}

__global__ void k_scan1(const int* __restrict__ count, int* start, int* bsum) {
    __shared__ int s[256];
    int i = blockIdx.x * 256 + threadIdx.x;
    int v = (i < N_NODES) ? count[i] : 0;
    s[threadIdx.x] = v; __syncthreads();
    for (int off = 1; off < 256; off <<= 1) {
        int t = (threadIdx.x >= off) ? s[threadIdx.x - off] : 0;
        __syncthreads();
        s[threadIdx.x] += t;
        __syncthreads();
    }
    if (i < N_NODES) start[i] = s[threadIdx.x] - v;   // exclusive
    if (threadIdx.x == 255) bsum[blockIdx.x] = s[255];
}

__global__ void k_scan2(int* bsum) {
    __shared__ int s[512];
    int v = (threadIdx.x < NB1) ? bsum[threadIdx.x] : 0;
    s[threadIdx.x] = v; __syncthreads();
    for (int off = 1; off < 512; off <<= 1) {
        int t = (threadIdx.x >= off) ? s[threadIdx.x - off] : 0;
        __syncthreads();
        s[threadIdx.x] += t;
        __syncthreads();
    }
    if (threadIdx.x < NB1) bsum[threadIdx.x] = s[threadIdx.x] - v;  // exclusive
}

__global__ void k_scan3(int* start, const int* __restrict__ bsum) {
    int i = blockIdx.x * 256 + threadIdx.x;
    if (i < N_NODES) start[i] += bsum[i >> 8];
}

__global__ void k_scatter(const int* __restrict__ row, const int* __restrict__ col,
                          const float* __restrict__ ea, const float* __restrict__ dinv,
                          const int* __restrict__ start, int* cursor, int2* csr) {
    int e = blockIdx.x * 256 + threadIdx.x;
    if (e < N_EDGES) {
        int c = col[e], r = row[e];
        int pos = start[c] + atomicAdd(cursor + c, 1);
        float w = dinv[r] * ea[e] * dinv[c];
        csr[pos] = make_int2(r, __float_as_int(w));
    }
}

// ---------- weight packing into MFMA B-fragment layout ----------
// Wp index = ((nt*KS + ks)*64 + lane)*8 + j  <->  W[(ks*32 + (lane>>4)*8 + j)*NCOL + nt*16 + (lane&15)]
__global__ void k_packW1(const float* __restrict__ W1, unsigned short* Wp) {
    int idx = blockIdx.x * 256 + threadIdx.x;         // 8 nt * 8 ks * 64 * 8 = 32768
    if (idx < 32768) {
        int j = idx & 7, lane = (idx >> 3) & 63, ks = (idx >> 9) & 7, nt = idx >> 12;
        int m = lane & 15, q = lane >> 4;
        int k = ks * 32 + q * 8 + j;
        int n = nt * 16 + m;
        Wp[idx] = f2bf(W1[k * H_DIM + n]);
    }
}

__global__ void k_packW2(const float* __restrict__ W2, unsigned short* Wp) {
    int idx = blockIdx.x * 256 + threadIdx.x;         // 3 nt * 4 ks * 64 * 8 = 6144
    if (idx < 6144) {
        int j = idx & 7, lane = (idx >> 3) & 63, ks = (idx >> 9) & 3, nt = idx >> 11;
        int m = lane & 15, q = lane >> 4;
        int k = ks * 32 + q * 8 + j;
        int n = nt * 16 + m;
        Wp[idx] = (n < C_DIM) ? f2bf(W2[k * C_DIM + n]) : (unsigned short)0;
    }
}

// ---------- GEMM1: h(bf16) = x(f32) @ W1, per-wave 16 rows x 128 cols ----------
__global__ void k_gemm1(const float* __restrict__ x, const unsigned short* __restrict__ Wp,
                        unsigned short* __restrict__ h) {
    int tile = blockIdx.x;                 // 6250 tiles * 16 rows = 100000
    int lane = threadIdx.x & 63;
    int m = lane & 15, q = lane >> 4;
    f32x4 acc[8];
#pragma unroll
    for (int i = 0; i < 8; i++) acc[i] = (f32x4){0.f, 0.f, 0.f, 0.f};
    const float* xr = x + (long)(tile * 16 + m) * F_INPUT + q * 8;
#pragma unroll
    for (int ks = 0; ks < 8; ks++) {
        float4 a0 = *(const float4*)(xr + ks * 32);
        float4 a1 = *(const float4*)(xr + ks * 32 + 4);
        bf8 a;
        a[0] = (short)f2bf(a0.x); a[1] = (short)f2bf(a0.y);
        a[2] = (short)f2bf(a0.z); a[3] = (short)f2bf(a0.w);
        a[4] = (short)f2bf(a1.x); a[5] = (short)f2bf(a1.y);
        a[6] = (short)f2bf(a1.z); a[7] = (short)f2bf(a1.w);
#pragma unroll
        for (int nt = 0; nt < 8; nt++) {
            bf8 b = *(const bf8*)(Wp + (((nt * 8 + ks) * 64 + lane) << 3));
            acc[nt] = __builtin_amdgcn_mfma_f32_16x16x32_bf16(a, b, acc[nt], 0, 0, 0);
        }
    }
    int orow = tile * 16 + q * 4;
#pragma unroll
    for (int nt = 0; nt < 8; nt++)
#pragma unroll
        for (int r = 0; r < 4; r++)
            h[(long)(orow + r) * H_DIM + nt * 16 + m] = f2bf(acc[nt][r]);
}

// ---------- aggregation layer 1: h1 = relu(A_norm @ h + b1), wave per node ----------
__global__ void k_agg1(const unsigned short* __restrict__ h, const int2* __restrict__ csr,
                       const int* __restrict__ start, const int* __restrict__ count,
                       const float* __restrict__ dinv, const float* __restrict__ b1,
                       unsigned short* __restrict__ h1) {
    int c = (blockIdx.x * blockDim.x + threadIdx.x) >> 6;
    int lane = threadIdx.x & 63;
    if (c >= N_NODES) return;
    float di = dinv[c];
    float selfw = di * di;
    unsigned hv = *(const unsigned*)(h + (long)c * H_DIM + lane * 2);
    float a0 = selfw * bf2f((unsigned short)(hv & 0xFFFF));
    float a1 = selfw * bf2f((unsigned short)(hv >> 16));
    int s = start[c], e = s + count[c];
    int pos = s;
    for (; pos + 1 < e; pos += 2) {
        int2 p0 = csr[pos];
        int2 p1 = csr[pos + 1];
        unsigned v0 = *(const unsigned*)(h + (long)p0.x * H_DIM + lane * 2);
        unsigned v1 = *(const unsigned*)(h + (long)p1.x * H_DIM + lane * 2);
        float w0 = __int_as_float(p0.y), w1 = __int_as_float(p1.y);
        a0 += w0 * bf2f((unsigned short)(v0 & 0xFFFF)) + w1 * bf2f((unsigned short)(v1 & 0xFFFF));
        a1 += w0 * bf2f((unsigned short)(v0 >> 16))    + w1 * bf2f((unsigned short)(v1 >> 16));
    }
    if (pos < e) {
        int2 p0 = csr[pos];
        unsigned v0 = *(const unsigned*)(h + (long)p0.x * H_DIM + lane * 2);
        float w0 = __int_as_float(p0.y);
        a0 += w0 * bf2f((unsigned short)(v0 & 0xFFFF));
        a1 += w0 * bf2f((unsigned short)(v0 >> 16));
    }
    a0 = fmaxf(a0 + b1[lane * 2], 0.f);
    a1 = fmaxf(a1 + b1[lane * 2 + 1], 0.f);
    unsigned outv = (unsigned)f2bf(a0) | ((unsigned)f2bf(a1) << 16);
    *(unsigned*)(h1 + (long)c * H_DIM + lane * 2) = outv;
}

// ---------- GEMM2: h2(bf16) = h1(bf16) @ W2, per-wave 16 rows x 48(40) cols ----------
__global__ void k_gemm2(const unsigned short* __restrict__ h1, const unsigned short* __restrict__ Wp,
                        unsigned short* __restrict__ h2) {
    int tile = blockIdx.x;
    int lane = threadIdx.x & 63;
    int m = lane & 15, q = lane >> 4;
    f32x4 acc[3];
#pragma unroll
    for (int i = 0; i < 3; i++) acc[i] = (f32x4){0.f, 0.f, 0.f, 0.f};
    const unsigned short* hr = h1 + (long)(tile * 16 + m) * H_DIM + q * 8;
#pragma unroll
    for (int ks = 0; ks < 4; ks++) {
        bf8 a = *(const bf8*)(hr + ks * 32);
#pragma unroll
        for (int nt = 0; nt < 3; nt++) {
            bf8 b = *(const bf8*)(Wp + (((nt * 4 + ks) * 64 + lane) << 3));
            acc[nt] = __builtin_amdgcn_mfma_f32_16x16x32_bf16(a, b, acc[nt], 0, 0, 0);
        }
    }
    int orow = tile * 16 + q * 4;
#pragma unroll
    for (int nt = 0; nt < 3; nt++)
#pragma unroll
        for (int r = 0; r < 4; r++) {
            int colo = nt * 16 + m;
            if (colo < C_DIM)
                h2[(long)(orow + r) * C_DIM + colo] = f2bf(acc[nt][r]);
        }
}

// ---------- aggregation layer 2 + bias + log_softmax, wave per node ----------
__global__ void k_agg2(const unsigned short* __restrict__ h2, const int2* __restrict__ csr,
                       const int* __restrict__ start, const int* __restrict__ count,
                       const float* __restrict__ dinv, const float* __restrict__ b2,
                       float* __restrict__ out) {
    int c = (blockIdx.x * blockDim.x + threadIdx.x) >> 6;
    int lane = threadIdx.x & 63;
    if (c >= N_NODES) return;
    float di = dinv[c];
    float selfw = di * di;
    float acc = 0.f;
    if (lane < C_DIM) acc = selfw * bf2f(h2[(long)c * C_DIM + lane]);
    int s = start[c], e = s + count[c];
    int pos = s;
    for (; pos + 1 < e; pos += 2) {
        int2 p0 = csr[pos];
        int2 p1 = csr[pos + 1];
        if (lane < C_DIM) {
            acc += __int_as_float(p0.y) * bf2f(h2[(long)p0.x * C_DIM + lane]);
            acc += __int_as_float(p1.y) * bf2f(h2[(long)p1.x * C_DIM + lane]);
        }
    }
    if (pos < e) {
        int2 p0 = csr[pos];
        if (lane < C_DIM) acc += __int_as_float(p0.y) * bf2f(h2[(long)p0.x * C_DIM + lane]);
    }
    float v = (lane < C_DIM) ? acc + b2[lane] : -INFINITY;
    float mx = v;
#pragma unroll
    for (int off = 32; off; off >>= 1) mx = fmaxf(mx, __shfl_xor(mx, off));
    float ex = (lane < C_DIM) ? __expf(v - mx) : 0.f;
    float sm = ex;
#pragma unroll
    for (int off = 32; off; off >>= 1) sm += __shfl_xor(sm, off);
    if (lane < C_DIM) out[(long)c * C_DIM + lane] = v - mx - logf(sm);
}

extern "C" void kernel_launch(void* const* d_in, const int* in_sizes, int n_in,
                              void* d_out, int out_size, void* d_ws, size_t ws_size,
                              hipStream_t stream) {
    const float* x  = (const float*)d_in[0];
    const int*   ei = (const int*)d_in[1];
    const float* ea = (const float*)d_in[2];
    const float* W1 = (const float*)d_in[3];
    const float* b1 = (const float*)d_in[4];
    const float* W2 = (const float*)d_in[5];
    const float* b2 = (const float*)d_in[6];
    const int* row = ei;
    const int* col = ei + N_EDGES;

    char* ws = (char*)d_ws;
    size_t off = 0;
    auto alloc = [&](size_t bytes) -> void* {
        void* p = ws + off;
        off = (off + bytes + 255) & ~(size_t)255;
        return p;
    };
    float*          dinv   = (float*)alloc((size_t)N_NODES * 4);
    int*            count  = (int*)alloc((size_t)N_NODES * 4);
    int*            cursor = (int*)alloc((size_t)N_NODES * 4);
    int*            start  = (int*)alloc((size_t)N_NODES * 4);
    int*            bsum   = (int*)alloc(512 * 4);
    int2*           csr    = (int2*)alloc((size_t)N_EDGES * 8);
    unsigned short* Wp1    = (unsigned short*)alloc(32768 * 2);
    unsigned short* Wp2    = (unsigned short*)alloc(6144 * 2);
    unsigned short* h      = (unsigned short*)alloc((size_t)N_NODES * H_DIM * 2);
    unsigned short* h1     = (unsigned short*)alloc((size_t)N_NODES * H_DIM * 2);
    unsigned short* h2     = (unsigned short*)alloc((size_t)N_NODES * C_DIM * 2);

    k_init<<<NB1, 256, 0, stream>>>(dinv, count, cursor);
    k_count<<<N_EDGES / 256, 256, 0, stream>>>(col, ea, dinv, count);
    k_rsqrt<<<NB1, 256, 0, stream>>>(dinv);
    k_scan1<<<NB1, 256, 0, stream>>>(count, start, bsum);
    k_scan2<<<1, 512, 0, stream>>>(bsum);
    k_scan3<<<NB1, 256, 0, stream>>>(start, bsum);
    k_scatter<<<N_EDGES / 256, 256, 0, stream>>>(row, col, ea, dinv, start, cursor, csr);
    k_packW1<<<128, 256, 0, stream>>>(W1, Wp1);
    k_packW2<<<24, 256, 0, stream>>>(W2, Wp2);
    k_gemm1<<<N_NODES / 16, 64, 0, stream>>>(x, Wp1, h);
    k_agg1<<<N_NODES / 4, 256, 0, stream>>>(h, csr, start, count, dinv, b1, h1);
    k_gemm2<<<N_NODES / 16, 64, 0, stream>>>(h1, Wp2, h2);
    k_agg2<<<N_NODES / 4, 256, 0, stream>>>(h2, csr, start, count, dinv, b2, (float*)d_out);
}

// Round 2
// 553.147 us; speedup vs baseline: 1.1765x; 1.1765x over previous
//
#include <hip/hip_runtime.h>

#define N_NODES 100000
#define N_EDGES 1600000
#define F_INPUT 256
#define H_DIM   128
#define C_DIM   40
#define NB1     ((N_NODES + 255) / 256)   // 391 scan blocks

typedef short  bf8   __attribute__((ext_vector_type(8)));
typedef float  f32x4 __attribute__((ext_vector_type(4)));

static __device__ __forceinline__ unsigned short f2bf(float f) {
    union { float f; unsigned u; } v; v.f = f;
    unsigned r = v.u + 0x7FFFu + ((v.u >> 16) & 1u);
    return (unsigned short)(r >> 16);
}
static __device__ __forceinline__ float bf2f(unsigned short b) {
    union { unsigned u; float f; } v; v.u = ((unsigned)b) << 16;
    return v.f;
}

// ---------- norm preprocessing ----------
// packed[c]: bits[40:63] = edge count into c, bits[0:39] = sum(ea) in Q24 fixed point.
// deg = 1.0 (self loop) + sum(ea); init packed with 1.0 in Q24.
__global__ void k_init(unsigned long long* packed) {
    int i = blockIdx.x * 256 + threadIdx.x;
    if (i < N_NODES) packed[i] = (1ull << 24);
}

// ONE random atomic per edge; returned old value's count field = this edge's
// rank among same-destination edges -> used later for atomic-free scatter.
__global__ void k_count(const int* __restrict__ col, const float* __restrict__ ea,
                        unsigned long long* packed, int* __restrict__ rank) {
    int e = blockIdx.x * 256 + threadIdx.x;
    if (e < N_EDGES) {
        int c = col[e];
        unsigned q = __float2uint_rn(ea[e] * 16777216.0f);   // Q24
        unsigned long long add = (1ull << 40) | (unsigned long long)q;
        unsigned long long old = atomicAdd(packed + c, add);
        rank[e] = (int)(old >> 40);
    }
}

__global__ void k_rsqrt(const unsigned long long* __restrict__ packed, float* dinv) {
    int i = blockIdx.x * 256 + threadIdx.x;
    if (i < N_NODES) {
        float deg = (float)(packed[i] & ((1ull << 40) - 1)) * (1.0f / 16777216.0f);
        dinv[i] = rsqrtf(deg);   // deg >= 1 always (self-loop)
    }
}

__global__ void k_scan1(const unsigned long long* __restrict__ packed, int* start, int* bsum) {
    __shared__ int s[256];
    int i = blockIdx.x * 256 + threadIdx.x;
    int v = (i < N_NODES) ? (int)(packed[i] >> 40) : 0;
    s[threadIdx.x] = v; __syncthreads();
    for (int off = 1; off < 256; off <<= 1) {
        int t = (threadIdx.x >= off) ? s[threadIdx.x - off] : 0;
        __syncthreads();
        s[threadIdx.x] += t;
        __syncthreads();
    }
    if (i < N_NODES) start[i] = s[threadIdx.x] - v;   // exclusive
    if (threadIdx.x == 255) bsum[blockIdx.x] = s[255];
}

__global__ void k_scan2(int* bsum) {
    __shared__ int s[512];
    int v = (threadIdx.x < NB1) ? bsum[threadIdx.x] : 0;
    s[threadIdx.x] = v; __syncthreads();
    for (int off = 1; off < 512; off <<= 1) {
        int t = (threadIdx.x >= off) ? s[threadIdx.x - off] : 0;
        __syncthreads();
        s[threadIdx.x] += t;
        __syncthreads();
    }
    if (threadIdx.x < NB1) bsum[threadIdx.x] = s[threadIdx.x] - v;  // exclusive
}

__global__ void k_scan3(int* start, const int* __restrict__ bsum) {
    int i = blockIdx.x * 256 + threadIdx.x;
    if (i < N_NODES) start[i] += bsum[i >> 8];
}

// atomic-free scatter: position = start[dest] + precomputed rank
__global__ void k_scatter(const int* __restrict__ row, const int* __restrict__ col,
                          const float* __restrict__ ea, const float* __restrict__ dinv,
                          const int* __restrict__ start, const int* __restrict__ rank,
                          int2* __restrict__ csr) {
    int e = blockIdx.x * 256 + threadIdx.x;
    if (e < N_EDGES) {
        int c = col[e], r = row[e];
        int pos = start[c] + rank[e];
        float w = dinv[r] * ea[e] * dinv[c];
        csr[pos] = make_int2(r, __float_as_int(w));
    }
}

// ---------- weight packing into MFMA B-fragment layout ----------
// Wp index = ((nt*KS + ks)*64 + lane)*8 + j  <->  W[(ks*32 + (lane>>4)*8 + j)*NCOL + nt*16 + (lane&15)]
__global__ void k_packW1(const float* __restrict__ W1, unsigned short* Wp) {
    int idx = blockIdx.x * 256 + threadIdx.x;         // 8 nt * 8 ks * 64 * 8 = 32768
    if (idx < 32768) {
        int j = idx & 7, lane = (idx >> 3) & 63, ks = (idx >> 9) & 7, nt = idx >> 12;
        int m = lane & 15, q = lane >> 4;
        int k = ks * 32 + q * 8 + j;
        int n = nt * 16 + m;
        Wp[idx] = f2bf(W1[k * H_DIM + n]);
    }
}

__global__ void k_packW2(const float* __restrict__ W2, unsigned short* Wp) {
    int idx = blockIdx.x * 256 + threadIdx.x;         // 3 nt * 4 ks * 64 * 8 = 6144
    if (idx < 6144) {
        int j = idx & 7, lane = (idx >> 3) & 63, ks = (idx >> 9) & 3, nt = idx >> 11;
        int m = lane & 15, q = lane >> 4;
        int k = ks * 32 + q * 8 + j;
        int n = nt * 16 + m;
        Wp[idx] = (n < C_DIM) ? f2bf(W2[k * C_DIM + n]) : (unsigned short)0;
    }
}

// ---------- GEMM1: h(bf16) = x(f32) @ W1, per-wave 16 rows x 128 cols ----------
__global__ void k_gemm1(const float* __restrict__ x, const unsigned short* __restrict__ Wp,
                        unsigned short* __restrict__ h) {
    int tile = blockIdx.x;                 // 6250 tiles * 16 rows = 100000
    int lane = threadIdx.x & 63;
    int m = lane & 15, q = lane >> 4;
    f32x4 acc[8];
#pragma unroll
    for (int i = 0; i < 8; i++) acc[i] = (f32x4){0.f, 0.f, 0.f, 0.f};
    const float* xr = x + (long)(tile * 16 + m) * F_INPUT + q * 8;
#pragma unroll
    for (int ks = 0; ks < 8; ks++) {
        float4 a0 = *(const float4*)(xr + ks * 32);
        float4 a1 = *(const float4*)(xr + ks * 32 + 4);
        bf8 a;
        a[0] = (short)f2bf(a0.x); a[1] = (short)f2bf(a0.y);
        a[2] = (short)f2bf(a0.z); a[3] = (short)f2bf(a0.w);
        a[4] = (short)f2bf(a1.x); a[5] = (short)f2bf(a1.y);
        a[6] = (short)f2bf(a1.z); a[7] = (short)f2bf(a1.w);
#pragma unroll
        for (int nt = 0; nt < 8; nt++) {
            bf8 b = *(const bf8*)(Wp + (((nt * 8 + ks) * 64 + lane) << 3));
            acc[nt] = __builtin_amdgcn_mfma_f32_16x16x32_bf16(a, b, acc[nt], 0, 0, 0);
        }
    }
    int orow = tile * 16 + q * 4;
#pragma unroll
    for (int nt = 0; nt < 8; nt++)
#pragma unroll
        for (int r = 0; r < 4; r++)
            h[(long)(orow + r) * H_DIM + nt * 16 + m] = f2bf(acc[nt][r]);
}

// ---------- aggregation layer 1: h1 = relu(A_norm @ h + b1), wave per node ----------
__global__ void k_agg1(const unsigned short* __restrict__ h, const int2* __restrict__ csr,
                       const int* __restrict__ start, const unsigned long long* __restrict__ packed,
                       const float* __restrict__ dinv, const float* __restrict__ b1,
                       unsigned short* __restrict__ h1) {
    int c = (blockIdx.x * blockDim.x + threadIdx.x) >> 6;
    int lane = threadIdx.x & 63;
    if (c >= N_NODES) return;
    float di = dinv[c];
    float selfw = di * di;
    unsigned hv = *(const unsigned*)(h + (long)c * H_DIM + lane * 2);
    float a0 = selfw * bf2f((unsigned short)(hv & 0xFFFF));
    float a1 = selfw * bf2f((unsigned short)(hv >> 16));
    int s = start[c], e = s + (int)(packed[c] >> 40);
    int pos = s;
    for (; pos + 1 < e; pos += 2) {
        int2 p0 = csr[pos];
        int2 p1 = csr[pos + 1];
        unsigned v0 = *(const unsigned*)(h + (long)p0.x * H_DIM + lane * 2);
        unsigned v1 = *(const unsigned*)(h + (long)p1.x * H_DIM + lane * 2);
        float w0 = __int_as_float(p0.y), w1 = __int_as_float(p1.y);
        a0 += w0 * bf2f((unsigned short)(v0 & 0xFFFF)) + w1 * bf2f((unsigned short)(v1 & 0xFFFF));
        a1 += w0 * bf2f((unsigned short)(v0 >> 16))    + w1 * bf2f((unsigned short)(v1 >> 16));
    }
    if (pos < e) {
        int2 p0 = csr[pos];
        unsigned v0 = *(const unsigned*)(h + (long)p0.x * H_DIM + lane * 2);
        float w0 = __int_as_float(p0.y);
        a0 += w0 * bf2f((unsigned short)(v0 & 0xFFFF));
        a1 += w0 * bf2f((unsigned short)(v0 >> 16));
    }
    a0 = fmaxf(a0 + b1[lane * 2], 0.f);
    a1 = fmaxf(a1 + b1[lane * 2 + 1], 0.f);
    unsigned outv = (unsigned)f2bf(a0) | ((unsigned)f2bf(a1) << 16);
    *(unsigned*)(h1 + (long)c * H_DIM + lane * 2) = outv;
}

// ---------- GEMM2: h2(bf16) = h1(bf16) @ W2, per-wave 16 rows x 48(40) cols ----------
__global__ void k_gemm2(const unsigned short* __restrict__ h1, const unsigned short* __restrict__ Wp,
                        unsigned short* __restrict__ h2) {
    int tile = blockIdx.x;
    int lane = threadIdx.x & 63;
    int m = lane & 15, q = lane >> 4;
    f32x4 acc[3];
#pragma unroll
    for (int i = 0; i < 3; i++) acc[i] = (f32x4){0.f, 0.f, 0.f, 0.f};
    const unsigned short* hr = h1 + (long)(tile * 16 + m) * H_DIM + q * 8;
#pragma unroll
    for (int ks = 0; ks < 4; ks++) {
        bf8 a = *(const bf8*)(hr + ks * 32);
#pragma unroll
        for (int nt = 0; nt < 3; nt++) {
            bf8 b = *(const bf8*)(Wp + (((nt * 4 + ks) * 64 + lane) << 3));
            acc[nt] = __builtin_amdgcn_mfma_f32_16x16x32_bf16(a, b, acc[nt], 0, 0, 0);
        }
    }
    int orow = tile * 16 + q * 4;
#pragma unroll
    for (int nt = 0; nt < 3; nt++)
#pragma unroll
        for (int r = 0; r < 4; r++) {
            int colo = nt * 16 + m;
            if (colo < C_DIM)
                h2[(long)(orow + r) * C_DIM + colo] = f2bf(acc[nt][r]);
        }
}

// ---------- aggregation layer 2 + bias + log_softmax, wave per node ----------
__global__ void k_agg2(const unsigned short* __restrict__ h2, const int2* __restrict__ csr,
                       const int* __restrict__ start, const unsigned long long* __restrict__ packed,
                       const float* __restrict__ dinv, const float* __restrict__ b2,
                       float* __restrict__ out) {
    int c = (blockIdx.x * blockDim.x + threadIdx.x) >> 6;
    int lane = threadIdx.x & 63;
    if (c >= N_NODES) return;
    float di = dinv[c];
    float selfw = di * di;
    float acc = 0.f;
    if (lane < C_DIM) acc = selfw * bf2f(h2[(long)c * C_DIM + lane]);
    int s = start[c], e = s + (int)(packed[c] >> 40);
    int pos = s;
    for (; pos + 1 < e; pos += 2) {
        int2 p0 = csr[pos];
        int2 p1 = csr[pos + 1];
        if (lane < C_DIM) {
            acc += __int_as_float(p0.y) * bf2f(h2[(long)p0.x * C_DIM + lane]);
            acc += __int_as_float(p1.y) * bf2f(h2[(long)p1.x * C_DIM + lane]);
        }
    }
    if (pos < e) {
        int2 p0 = csr[pos];
        if (lane < C_DIM) acc += __int_as_float(p0.y) * bf2f(h2[(long)p0.x * C_DIM + lane]);
    }
    float v = (lane < C_DIM) ? acc + b2[lane] : -INFINITY;
    float mx = v;
#pragma unroll
    for (int off = 32; off; off >>= 1) mx = fmaxf(mx, __shfl_xor(mx, off));
    float ex = (lane < C_DIM) ? __expf(v - mx) : 0.f;
    float sm = ex;
#pragma unroll
    for (int off = 32; off; off >>= 1) sm += __shfl_xor(sm, off);
    if (lane < C_DIM) out[(long)c * C_DIM + lane] = v - mx - logf(sm);
}

extern "C" void kernel_launch(void* const* d_in, const int* in_sizes, int n_in,
                              void* d_out, int out_size, void* d_ws, size_t ws_size,
                              hipStream_t stream) {
    const float* x  = (const float*)d_in[0];
    const int*   ei = (const int*)d_in[1];
    const float* ea = (const float*)d_in[2];
    const float* W1 = (const float*)d_in[3];
    const float* b1 = (const float*)d_in[4];
    const float* W2 = (const float*)d_in[5];
    const float* b2 = (const float*)d_in[6];
    const int* row = ei;
    const int* col = ei + N_EDGES;

    char* ws = (char*)d_ws;
    size_t off = 0;
    auto alloc = [&](size_t bytes) -> void* {
        void* p = ws + off;
        off = (off + bytes + 255) & ~(size_t)255;
        return p;
    };
    unsigned long long* packed = (unsigned long long*)alloc((size_t)N_NODES * 8);
    float*          dinv   = (float*)alloc((size_t)N_NODES * 4);
    int*            rank   = (int*)alloc((size_t)N_EDGES * 4);
    int*            start  = (int*)alloc((size_t)N_NODES * 4);
    int*            bsum   = (int*)alloc(512 * 4);
    int2*           csr    = (int2*)alloc((size_t)N_EDGES * 8);
    unsigned short* Wp1    = (unsigned short*)alloc(32768 * 2);
    unsigned short* Wp2    = (unsigned short*)alloc(6144 * 2);
    unsigned short* h      = (unsigned short*)alloc((size_t)N_NODES * H_DIM * 2);
    unsigned short* h1     = (unsigned short*)alloc((size_t)N_NODES * H_DIM * 2);
    unsigned short* h2     = (unsigned short*)alloc((size_t)N_NODES * C_DIM * 2);

    k_init<<<NB1, 256, 0, stream>>>(packed);
    k_count<<<N_EDGES / 256, 256, 0, stream>>>(col, ea, packed, rank);
    k_rsqrt<<<NB1, 256, 0, stream>>>(packed, dinv);
    k_scan1<<<NB1, 256, 0, stream>>>(packed, start, bsum);
    k_scan2<<<1, 512, 0, stream>>>(bsum);
    k_scan3<<<NB1, 256, 0, stream>>>(start, bsum);
    k_scatter<<<N_EDGES / 256, 256, 0, stream>>>(row, col, ea, dinv, start, rank, csr);
    k_packW1<<<128, 256, 0, stream>>>(W1, Wp1);
    k_packW2<<<24, 256, 0, stream>>>(W2, Wp2);
    k_gemm1<<<N_NODES / 16, 64, 0, stream>>>(x, Wp1, h);
    k_agg1<<<N_NODES / 4, 256, 0, stream>>>(h, csr, start, packed, dinv, b1, h1);
    k_gemm2<<<N_NODES / 16, 64, 0, stream>>>(h1, Wp2, h2);
    k_agg2<<<N_NODES / 4, 256, 0, stream>>>(h2, csr, start, packed, dinv, b2, (float*)d_out);
}

// Round 3
// 484.715 us; speedup vs baseline: 1.3426x; 1.1412x over previous
//
#include <hip/hip_runtime.h>

#define N_NODES 100000
#define N_EDGES 1600000
#define F_INPUT 256
#define H_DIM   128
#define C_DIM   40
#define NB1     ((N_NODES + 255) / 256)   // 391 scan blocks

typedef short  bf8   __attribute__((ext_vector_type(8)));
typedef float  f32x4 __attribute__((ext_vector_type(4)));
typedef unsigned short u16x8 __attribute__((ext_vector_type(8)));

static __device__ __forceinline__ unsigned short f2bf(float f) {
    union { float f; unsigned u; } v; v.f = f;
    unsigned r = v.u + 0x7FFFu + ((v.u >> 16) & 1u);
    return (unsigned short)(r >> 16);
}
static __device__ __forceinline__ float bf2f(unsigned short b) {
    union { unsigned u; float f; } v; v.u = ((unsigned)b) << 16;
    return v.f;
}

// ---------- norm preprocessing ----------
// packed[c]: bits[40:63] = edge count into c, bits[0:39] = sum(ea) in Q24 fixed point.
__global__ void k_init(unsigned long long* packed) {
    int i = blockIdx.x * 256 + threadIdx.x;
    if (i < N_NODES) packed[i] = (1ull << 24);
}

// ONE random atomic per edge; old value's count field = edge's rank at its dest.
__global__ void k_count(const int* __restrict__ col, const float* __restrict__ ea,
                        unsigned long long* packed, int* __restrict__ rank) {
    int e = blockIdx.x * 256 + threadIdx.x;
    if (e < N_EDGES) {
        int c = col[e];
        unsigned q = __float2uint_rn(ea[e] * 16777216.0f);   // Q24
        unsigned long long add = (1ull << 40) | (unsigned long long)q;
        unsigned long long old = atomicAdd(packed + c, add);
        rank[e] = (int)(old >> 40);
    }
}

__global__ void k_rsqrt(const unsigned long long* __restrict__ packed, float* dinv) {
    int i = blockIdx.x * 256 + threadIdx.x;
    if (i < N_NODES) {
        float deg = (float)(packed[i] & ((1ull << 40) - 1)) * (1.0f / 16777216.0f);
        dinv[i] = rsqrtf(deg);
    }
}

__global__ void k_scan1(const unsigned long long* __restrict__ packed, int* start, int* bsum) {
    __shared__ int s[256];
    int i = blockIdx.x * 256 + threadIdx.x;
    int v = (i < N_NODES) ? (int)(packed[i] >> 40) : 0;
    s[threadIdx.x] = v; __syncthreads();
    for (int off = 1; off < 256; off <<= 1) {
        int t = (threadIdx.x >= off) ? s[threadIdx.x - off] : 0;
        __syncthreads();
        s[threadIdx.x] += t;
        __syncthreads();
    }
    if (i < N_NODES) start[i] = s[threadIdx.x] - v;
    if (threadIdx.x == 255) bsum[blockIdx.x] = s[255];
}

__global__ void k_scan2(int* bsum) {
    __shared__ int s[512];
    int v = (threadIdx.x < NB1) ? bsum[threadIdx.x] : 0;
    s[threadIdx.x] = v; __syncthreads();
    for (int off = 1; off < 512; off <<= 1) {
        int t = (threadIdx.x >= off) ? s[threadIdx.x - off] : 0;
        __syncthreads();
        s[threadIdx.x] += t;
        __syncthreads();
    }
    if (threadIdx.x < NB1) bsum[threadIdx.x] = s[threadIdx.x] - v;
}

__global__ void k_scan3(int* start, const int* __restrict__ bsum) {
    int i = blockIdx.x * 256 + threadIdx.x;
    if (i < N_NODES) start[i] += bsum[i >> 8];
}

// atomic-free scatter: position = start[dest] + precomputed rank
__global__ void k_scatter(const int* __restrict__ row, const int* __restrict__ col,
                          const float* __restrict__ ea, const float* __restrict__ dinv,
                          const int* __restrict__ start, const int* __restrict__ rank,
                          int2* __restrict__ csr) {
    int e = blockIdx.x * 256 + threadIdx.x;
    if (e < N_EDGES) {
        int c = col[e], r = row[e];
        int pos = start[c] + rank[e];
        float w = dinv[r] * ea[e] * dinv[c];
        csr[pos] = make_int2(r, __float_as_int(w));
    }
}

// ---------- weight packing into MFMA B-fragment layout ----------
__global__ void k_packW1(const float* __restrict__ W1, unsigned short* Wp) {
    int idx = blockIdx.x * 256 + threadIdx.x;         // 32768
    if (idx < 32768) {
        int j = idx & 7, lane = (idx >> 3) & 63, ks = (idx >> 9) & 7, nt = idx >> 12;
        int m = lane & 15, q = lane >> 4;
        int k = ks * 32 + q * 8 + j;
        int n = nt * 16 + m;
        Wp[idx] = f2bf(W1[k * H_DIM + n]);
    }
}

__global__ void k_packW2(const float* __restrict__ W2, unsigned short* Wp) {
    int idx = blockIdx.x * 256 + threadIdx.x;         // 6144
    if (idx < 6144) {
        int j = idx & 7, lane = (idx >> 3) & 63, ks = (idx >> 9) & 3, nt = idx >> 11;
        int m = lane & 15, q = lane >> 4;
        int k = ks * 32 + q * 8 + j;
        int n = nt * 16 + m;
        Wp[idx] = (n < C_DIM) ? f2bf(W2[k * C_DIM + n]) : (unsigned short)0;
    }
}

// ---------- GEMM1: h(bf16) = x(f32) @ W1, per-wave 16 rows x 128 cols ----------
__global__ void k_gemm1(const float* __restrict__ x, const unsigned short* __restrict__ Wp,
                        unsigned short* __restrict__ h) {
    int tile = blockIdx.x;
    int lane = threadIdx.x & 63;
    int m = lane & 15, q = lane >> 4;
    f32x4 acc[8];
#pragma unroll
    for (int i = 0; i < 8; i++) acc[i] = (f32x4){0.f, 0.f, 0.f, 0.f};
    const float* xr = x + (long)(tile * 16 + m) * F_INPUT + q * 8;
#pragma unroll
    for (int ks = 0; ks < 8; ks++) {
        float4 a0 = *(const float4*)(xr + ks * 32);
        float4 a1 = *(const float4*)(xr + ks * 32 + 4);
        bf8 a;
        a[0] = (short)f2bf(a0.x); a[1] = (short)f2bf(a0.y);
        a[2] = (short)f2bf(a0.z); a[3] = (short)f2bf(a0.w);
        a[4] = (short)f2bf(a1.x); a[5] = (short)f2bf(a1.y);
        a[6] = (short)f2bf(a1.z); a[7] = (short)f2bf(a1.w);
#pragma unroll
        for (int nt = 0; nt < 8; nt++) {
            bf8 b = *(const bf8*)(Wp + (((nt * 8 + ks) * 64 + lane) << 3));
            acc[nt] = __builtin_amdgcn_mfma_f32_16x16x32_bf16(a, b, acc[nt], 0, 0, 0);
        }
    }
    int orow = tile * 16 + q * 4;
#pragma unroll
    for (int nt = 0; nt < 8; nt++)
#pragma unroll
        for (int r = 0; r < 4; r++)
            h[(long)(orow + r) * H_DIM + nt * 16 + m] = f2bf(acc[nt][r]);
}

// ---------- aggregation layer 1: wave/node, 4-way edge-parallel, 16 B gathers ----------
// lane = eg*16 + cl;  eg in [0,4): edge group;  cl in [0,16): 8-feature chunk
__global__ void k_agg1(const unsigned short* __restrict__ h, const int2* __restrict__ csr,
                       const int* __restrict__ start, const unsigned long long* __restrict__ packed,
                       const float* __restrict__ dinv, const float* __restrict__ b1,
                       unsigned short* __restrict__ h1) {
    int c = (blockIdx.x * blockDim.x + threadIdx.x) >> 6;
    int lane = threadIdx.x & 63;
    if (c >= N_NODES) return;
    int eg = lane >> 4, cl = lane & 15;
    float di = dinv[c];
    float acc[8];
#pragma unroll
    for (int j = 0; j < 8; j++) acc[j] = 0.f;
    if (eg == 0) {                                    // self loop, weight dinv^2
        float selfw = di * di;
        bf8 v = *(const bf8*)(h + (long)c * H_DIM + cl * 8);
#pragma unroll
        for (int j = 0; j < 8; j++) acc[j] += selfw * bf2f((unsigned short)v[j]);
    }
    int s = start[c], n = (int)(packed[c] >> 40);
    for (int i = eg; i < n; i += 4) {
        int2 p = csr[s + i];
        bf8 v = *(const bf8*)(h + (long)p.x * H_DIM + cl * 8);
        float w = __int_as_float(p.y);
#pragma unroll
        for (int j = 0; j < 8; j++) acc[j] += w * bf2f((unsigned short)v[j]);
    }
#pragma unroll
    for (int j = 0; j < 8; j++) {
        acc[j] += __shfl_xor(acc[j], 16);
        acc[j] += __shfl_xor(acc[j], 32);
    }
    if (eg == 0) {
        u16x8 o;
#pragma unroll
        for (int j = 0; j < 8; j++) o[j] = f2bf(fmaxf(acc[j] + b1[cl * 8 + j], 0.f));
        *(u16x8*)(h1 + (long)c * H_DIM + cl * 8) = o;
    }
}

// ---------- GEMM2: h2(bf16) = h1(bf16) @ W2 ----------
__global__ void k_gemm2(const unsigned short* __restrict__ h1, const unsigned short* __restrict__ Wp,
                        unsigned short* __restrict__ h2) {
    int tile = blockIdx.x;
    int lane = threadIdx.x & 63;
    int m = lane & 15, q = lane >> 4;
    f32x4 acc[3];
#pragma unroll
    for (int i = 0; i < 3; i++) acc[i] = (f32x4){0.f, 0.f, 0.f, 0.f};
    const unsigned short* hr = h1 + (long)(tile * 16 + m) * H_DIM + q * 8;
#pragma unroll
    for (int ks = 0; ks < 4; ks++) {
        bf8 a = *(const bf8*)(hr + ks * 32);
#pragma unroll
        for (int nt = 0; nt < 3; nt++) {
            bf8 b = *(const bf8*)(Wp + (((nt * 4 + ks) * 64 + lane) << 3));
            acc[nt] = __builtin_amdgcn_mfma_f32_16x16x32_bf16(a, b, acc[nt], 0, 0, 0);
        }
    }
    int orow = tile * 16 + q * 4;
#pragma unroll
    for (int nt = 0; nt < 3; nt++)
#pragma unroll
        for (int r = 0; r < 4; r++) {
            int colo = nt * 16 + m;
            if (colo < C_DIM)
                h2[(long)(orow + r) * C_DIM + colo] = f2bf(acc[nt][r]);
        }
}

// ---------- aggregation layer 2 + bias + log_softmax: wave/node, 8-way edge-parallel ----------
// lane = eg*8 + cl;  eg in [0,8);  cl in [0,8), cl<5 active (5*8=40 classes)
__global__ void k_agg2(const unsigned short* __restrict__ h2, const int2* __restrict__ csr,
                       const int* __restrict__ start, const unsigned long long* __restrict__ packed,
                       const float* __restrict__ dinv, const float* __restrict__ b2,
                       float* __restrict__ out) {
    int c = (blockIdx.x * blockDim.x + threadIdx.x) >> 6;
    int lane = threadIdx.x & 63;
    if (c >= N_NODES) return;
    int eg = lane >> 3, cl = lane & 7;
    float di = dinv[c];
    float acc[8];
#pragma unroll
    for (int j = 0; j < 8; j++) acc[j] = 0.f;
    if (eg == 0 && cl < 5) {
        float selfw = di * di;
        bf8 v = *(const bf8*)(h2 + (long)c * C_DIM + cl * 8);
#pragma unroll
        for (int j = 0; j < 8; j++) acc[j] += selfw * bf2f((unsigned short)v[j]);
    }
    int s = start[c], n = (int)(packed[c] >> 40);
    for (int i = eg; i < n; i += 8) {
        int2 p = csr[s + i];
        if (cl < 5) {
            bf8 v = *(const bf8*)(h2 + (long)p.x * C_DIM + cl * 8);
            float w = __int_as_float(p.y);
#pragma unroll
            for (int j = 0; j < 8; j++) acc[j] += w * bf2f((unsigned short)v[j]);
        }
    }
#pragma unroll
    for (int j = 0; j < 8; j++) {
        acc[j] += __shfl_xor(acc[j], 8);
        acc[j] += __shfl_xor(acc[j], 16);
        acc[j] += __shfl_xor(acc[j], 32);
    }
    // add bias; lanes cl>=5 are inert
    float v[8];
    float lm = -INFINITY;
    if (cl < 5) {
#pragma unroll
        for (int j = 0; j < 8; j++) {
            v[j] = acc[j] + b2[cl * 8 + j];
            lm = fmaxf(lm, v[j]);
        }
    }
    lm = fmaxf(lm, __shfl_xor(lm, 1));
    lm = fmaxf(lm, __shfl_xor(lm, 2));
    lm = fmaxf(lm, __shfl_xor(lm, 4));
    float ls = 0.f;
    if (cl < 5) {
#pragma unroll
        for (int j = 0; j < 8; j++) ls += __expf(v[j] - lm);
    }
    ls += __shfl_xor(ls, 1);
    ls += __shfl_xor(ls, 2);
    ls += __shfl_xor(ls, 4);
    if (eg == 0 && cl < 5) {
        float lsm = lm + logf(ls);
        f32x4 o0, o1;
#pragma unroll
        for (int j = 0; j < 4; j++) { o0[j] = v[j] - lsm; o1[j] = v[j + 4] - lsm; }
        *(f32x4*)(out + (long)c * C_DIM + cl * 8)     = o0;
        *(f32x4*)(out + (long)c * C_DIM + cl * 8 + 4) = o1;
    }
}

extern "C" void kernel_launch(void* const* d_in, const int* in_sizes, int n_in,
                              void* d_out, int out_size, void* d_ws, size_t ws_size,
                              hipStream_t stream) {
    const float* x  = (const float*)d_in[0];
    const int*   ei = (const int*)d_in[1];
    const float* ea = (const float*)d_in[2];
    const float* W1 = (const float*)d_in[3];
    const float* b1 = (const float*)d_in[4];
    const float* W2 = (const float*)d_in[5];
    const float* b2 = (const float*)d_in[6];
    const int* row = ei;
    const int* col = ei + N_EDGES;

    char* ws = (char*)d_ws;
    size_t off = 0;
    auto alloc = [&](size_t bytes) -> void* {
        void* p = ws + off;
        off = (off + bytes + 255) & ~(size_t)255;
        return p;
    };
    unsigned long long* packed = (unsigned long long*)alloc((size_t)N_NODES * 8);
    float*          dinv   = (float*)alloc((size_t)N_NODES * 4);
    int*            rank   = (int*)alloc((size_t)N_EDGES * 4);
    int*            start  = (int*)alloc((size_t)N_NODES * 4);
    int*            bsum   = (int*)alloc(512 * 4);
    int2*           csr    = (int2*)alloc((size_t)N_EDGES * 8);
    unsigned short* Wp1    = (unsigned short*)alloc(32768 * 2);
    unsigned short* Wp2    = (unsigned short*)alloc(6144 * 2);
    unsigned short* h      = (unsigned short*)alloc((size_t)N_NODES * H_DIM * 2);
    unsigned short* h1     = (unsigned short*)alloc((size_t)N_NODES * H_DIM * 2);
    unsigned short* h2     = (unsigned short*)alloc((size_t)N_NODES * C_DIM * 2);

    k_init<<<NB1, 256, 0, stream>>>(packed);
    k_count<<<N_EDGES / 256, 256, 0, stream>>>(col, ea, packed, rank);
    k_rsqrt<<<NB1, 256, 0, stream>>>(packed, dinv);
    k_scan1<<<NB1, 256, 0, stream>>>(packed, start, bsum);
    k_scan2<<<1, 512, 0, stream>>>(bsum);
    k_scan3<<<NB1, 256, 0, stream>>>(start, bsum);
    k_scatter<<<N_EDGES / 256, 256, 0, stream>>>(row, col, ea, dinv, start, rank, csr);
    k_packW1<<<128, 256, 0, stream>>>(W1, Wp1);
    k_packW2<<<24, 256, 0, stream>>>(W2, Wp2);
    k_gemm1<<<N_NODES / 16, 64, 0, stream>>>(x, Wp1, h);
    k_agg1<<<N_NODES / 4, 256, 0, stream>>>(h, csr, start, packed, dinv, b1, h1);
    k_gemm2<<<N_NODES / 16, 64, 0, stream>>>(h1, Wp2, h2);
    k_agg2<<<N_NODES / 4, 256, 0, stream>>>(h2, csr, start, packed, dinv, b2, (float*)d_out);
}

// Round 4
// 462.033 us; speedup vs baseline: 1.4085x; 1.0491x over previous
//
#include <hip/hip_runtime.h>

#define N_NODES 100000
#define N_EDGES 1600000
#define F_INPUT 256
#define H_DIM   128
#define C_DIM   40
#define NB1     ((N_NODES + 255) / 256)   // 391 scan blocks

typedef short  bf8   __attribute__((ext_vector_type(8)));
typedef float  f32x4 __attribute__((ext_vector_type(4)));
typedef unsigned short u16x8 __attribute__((ext_vector_type(8)));

static __device__ __forceinline__ unsigned short f2bf(float f) {
    union { float f; unsigned u; } v; v.f = f;
    unsigned r = v.u + 0x7FFFu + ((v.u >> 16) & 1u);
    return (unsigned short)(r >> 16);
}
static __device__ __forceinline__ float bf2f(unsigned short b) {
    union { unsigned u; float f; } v; v.u = ((unsigned)b) << 16;
    return v.f;
}

// ---------- norm preprocessing ----------
// packed[c]: bits[40:63] = edge count into c, bits[0:39] = sum(ea) in Q24 fixed point.
__global__ void k_init(unsigned long long* packed) {
    int i = blockIdx.x * 256 + threadIdx.x;
    if (i < N_NODES) packed[i] = (1ull << 24);
}

// ONE random atomic per edge; old value's count field = edge's rank at its dest.
__global__ void k_count(const int* __restrict__ col, const float* __restrict__ ea,
                        unsigned long long* packed, int* __restrict__ rank) {
    int e = blockIdx.x * 256 + threadIdx.x;
    if (e < N_EDGES) {
        int c = col[e];
        unsigned q = __float2uint_rn(ea[e] * 16777216.0f);   // Q24
        unsigned long long add = (1ull << 40) | (unsigned long long)q;
        unsigned long long old = atomicAdd(packed + c, add);
        rank[e] = (int)(old >> 40);
    }
}

__global__ void k_rsqrt(const unsigned long long* __restrict__ packed, float* dinv) {
    int i = blockIdx.x * 256 + threadIdx.x;
    if (i < N_NODES) {
        float deg = (float)(packed[i] & ((1ull << 40) - 1)) * (1.0f / 16777216.0f);
        dinv[i] = rsqrtf(deg);
    }
}

__global__ void k_scan1(const unsigned long long* __restrict__ packed, int* start, int* bsum) {
    __shared__ int s[256];
    int i = blockIdx.x * 256 + threadIdx.x;
    int v = (i < N_NODES) ? (int)(packed[i] >> 40) : 0;
    s[threadIdx.x] = v; __syncthreads();
    for (int off = 1; off < 256; off <<= 1) {
        int t = (threadIdx.x >= off) ? s[threadIdx.x - off] : 0;
        __syncthreads();
        s[threadIdx.x] += t;
        __syncthreads();
    }
    if (i < N_NODES) start[i] = s[threadIdx.x] - v;
    if (threadIdx.x == 255) bsum[blockIdx.x] = s[255];
}

__global__ void k_scan2(int* bsum) {
    __shared__ int s[512];
    int v = (threadIdx.x < NB1) ? bsum[threadIdx.x] : 0;
    s[threadIdx.x] = v; __syncthreads();
    for (int off = 1; off < 512; off <<= 1) {
        int t = (threadIdx.x >= off) ? s[threadIdx.x - off] : 0;
        __syncthreads();
        s[threadIdx.x] += t;
        __syncthreads();
    }
    if (threadIdx.x < NB1) bsum[threadIdx.x] = s[threadIdx.x] - v;
}

__global__ void k_scan3(int* start, const int* __restrict__ bsum) {
    int i = blockIdx.x * 256 + threadIdx.x;
    if (i < N_NODES) start[i] += bsum[i >> 8];
}

// atomic-free scatter; dinv folded into dense stages so csr = (row, raw ea).
// Only ONE random gather (start[c]) + one random 8B store per edge.
__global__ void k_scatter(const int* __restrict__ row, const int* __restrict__ col,
                          const float* __restrict__ ea,
                          const int* __restrict__ start, const int* __restrict__ rank,
                          int2* __restrict__ csr) {
    int e = blockIdx.x * 256 + threadIdx.x;
    if (e < N_EDGES) {
        int c = col[e];
        int pos = start[c] + rank[e];
        csr[pos] = make_int2(row[e], __float_as_int(ea[e]));
    }
}

// ---------- weight packing into MFMA B-fragment layout ----------
__global__ void k_packW1(const float* __restrict__ W1, unsigned short* Wp) {
    int idx = blockIdx.x * 256 + threadIdx.x;         // 32768
    if (idx < 32768) {
        int j = idx & 7, lane = (idx >> 3) & 63, ks = (idx >> 9) & 7, nt = idx >> 12;
        int m = lane & 15, q = lane >> 4;
        int k = ks * 32 + q * 8 + j;
        int n = nt * 16 + m;
        Wp[idx] = f2bf(W1[k * H_DIM + n]);
    }
}

__global__ void k_packW2(const float* __restrict__ W2, unsigned short* Wp) {
    int idx = blockIdx.x * 256 + threadIdx.x;         // 6144
    if (idx < 6144) {
        int j = idx & 7, lane = (idx >> 3) & 63, ks = (idx >> 9) & 3, nt = idx >> 11;
        int m = lane & 15, q = lane >> 4;
        int k = ks * 32 + q * 8 + j;
        int n = nt * 16 + m;
        Wp[idx] = (n < C_DIM) ? f2bf(W2[k * C_DIM + n]) : (unsigned short)0;
    }
}

// ---------- GEMM1: hs(bf16) = dinv * (x @ W1), per-wave 16 rows x 128 cols ----------
__global__ void k_gemm1(const float* __restrict__ x, const unsigned short* __restrict__ Wp,
                        const float* __restrict__ dinv, unsigned short* __restrict__ h) {
    int tile = blockIdx.x;
    int lane = threadIdx.x & 63;
    int m = lane & 15, q = lane >> 4;
    f32x4 acc[8];
#pragma unroll
    for (int i = 0; i < 8; i++) acc[i] = (f32x4){0.f, 0.f, 0.f, 0.f};
    const float* xr = x + (long)(tile * 16 + m) * F_INPUT + q * 8;
#pragma unroll
    for (int ks = 0; ks < 8; ks++) {
        float4 a0 = *(const float4*)(xr + ks * 32);
        float4 a1 = *(const float4*)(xr + ks * 32 + 4);
        bf8 a;
        a[0] = (short)f2bf(a0.x); a[1] = (short)f2bf(a0.y);
        a[2] = (short)f2bf(a0.z); a[3] = (short)f2bf(a0.w);
        a[4] = (short)f2bf(a1.x); a[5] = (short)f2bf(a1.y);
        a[6] = (short)f2bf(a1.z); a[7] = (short)f2bf(a1.w);
#pragma unroll
        for (int nt = 0; nt < 8; nt++) {
            bf8 b = *(const bf8*)(Wp + (((nt * 8 + ks) * 64 + lane) << 3));
            acc[nt] = __builtin_amdgcn_mfma_f32_16x16x32_bf16(a, b, acc[nt], 0, 0, 0);
        }
    }
    int orow = tile * 16 + q * 4;
    f32x4 dr = *(const f32x4*)(dinv + orow);     // scale rows by dinv
#pragma unroll
    for (int nt = 0; nt < 8; nt++)
#pragma unroll
        for (int r = 0; r < 4; r++)
            h[(long)(orow + r) * H_DIM + nt * 16 + m] = f2bf(acc[nt][r] * dr[r]);
}

// ---------- aggregation layer 1: wave/node, 4-way edge-parallel, 4x unrolled ----------
// h1[c] = relu(dinv[c]*(hs[c] + sum ea_e * hs[row_e]) + b1)
__global__ void k_agg1(const unsigned short* __restrict__ h, const int2* __restrict__ csr,
                       const int* __restrict__ start, const unsigned long long* __restrict__ packed,
                       const float* __restrict__ dinv, const float* __restrict__ b1,
                       unsigned short* __restrict__ h1) {
    int c = (blockIdx.x * blockDim.x + threadIdx.x) >> 6;
    int lane = threadIdx.x & 63;
    if (c >= N_NODES) return;
    int eg = lane >> 4, cl = lane & 15;
    float di = dinv[c];
    float acc[8];
#pragma unroll
    for (int j = 0; j < 8; j++) acc[j] = 0.f;
    if (eg == 0) {                                    // self loop, weight 1 (pre-scaled)
        bf8 v = *(const bf8*)(h + (long)c * H_DIM + cl * 8);
#pragma unroll
        for (int j = 0; j < 8; j++) acc[j] += bf2f((unsigned short)v[j]);
    }
    int s = start[c], n = (int)(packed[c] >> 40);
    int i = eg;
    for (; i + 12 < n; i += 16) {                     // 4 gathers in flight per lane
        int2 p0 = csr[s + i];
        int2 p1 = csr[s + i + 4];
        int2 p2 = csr[s + i + 8];
        int2 p3 = csr[s + i + 12];
        bf8 v0 = *(const bf8*)(h + (long)p0.x * H_DIM + cl * 8);
        bf8 v1 = *(const bf8*)(h + (long)p1.x * H_DIM + cl * 8);
        bf8 v2 = *(const bf8*)(h + (long)p2.x * H_DIM + cl * 8);
        bf8 v3 = *(const bf8*)(h + (long)p3.x * H_DIM + cl * 8);
        float w0 = __int_as_float(p0.y), w1 = __int_as_float(p1.y);
        float w2 = __int_as_float(p2.y), w3 = __int_as_float(p3.y);
#pragma unroll
        for (int j = 0; j < 8; j++)
            acc[j] += w0 * bf2f((unsigned short)v0[j]) + w1 * bf2f((unsigned short)v1[j])
                    + w2 * bf2f((unsigned short)v2[j]) + w3 * bf2f((unsigned short)v3[j]);
    }
    for (; i < n; i += 4) {
        int2 p = csr[s + i];
        bf8 v = *(const bf8*)(h + (long)p.x * H_DIM + cl * 8);
        float w = __int_as_float(p.y);
#pragma unroll
        for (int j = 0; j < 8; j++) acc[j] += w * bf2f((unsigned short)v[j]);
    }
#pragma unroll
    for (int j = 0; j < 8; j++) {
        acc[j] += __shfl_xor(acc[j], 16);
        acc[j] += __shfl_xor(acc[j], 32);
    }
    if (eg == 0) {
        u16x8 o;
#pragma unroll
        for (int j = 0; j < 8; j++) o[j] = f2bf(fmaxf(di * acc[j] + b1[cl * 8 + j], 0.f));
        *(u16x8*)(h1 + (long)c * H_DIM + cl * 8) = o;
    }
}

// ---------- GEMM2: h2s(bf16) = dinv * (h1 @ W2) ----------
__global__ void k_gemm2(const unsigned short* __restrict__ h1, const unsigned short* __restrict__ Wp,
                        const float* __restrict__ dinv, unsigned short* __restrict__ h2) {
    int tile = blockIdx.x;
    int lane = threadIdx.x & 63;
    int m = lane & 15, q = lane >> 4;
    f32x4 acc[3];
#pragma unroll
    for (int i = 0; i < 3; i++) acc[i] = (f32x4){0.f, 0.f, 0.f, 0.f};
    const unsigned short* hr = h1 + (long)(tile * 16 + m) * H_DIM + q * 8;
#pragma unroll
    for (int ks = 0; ks < 4; ks++) {
        bf8 a = *(const bf8*)(hr + ks * 32);
#pragma unroll
        for (int nt = 0; nt < 3; nt++) {
            bf8 b = *(const bf8*)(Wp + (((nt * 4 + ks) * 64 + lane) << 3));
            acc[nt] = __builtin_amdgcn_mfma_f32_16x16x32_bf16(a, b, acc[nt], 0, 0, 0);
        }
    }
    int orow = tile * 16 + q * 4;
    f32x4 dr = *(const f32x4*)(dinv + orow);
#pragma unroll
    for (int nt = 0; nt < 3; nt++)
#pragma unroll
        for (int r = 0; r < 4; r++) {
            int colo = nt * 16 + m;
            if (colo < C_DIM)
                h2[(long)(orow + r) * C_DIM + colo] = f2bf(acc[nt][r] * dr[r]);
        }
}

// ---------- aggregation layer 2 + bias + log_softmax: wave/node, 8-way edge-parallel, 2x unrolled ----------
__global__ void k_agg2(const unsigned short* __restrict__ h2, const int2* __restrict__ csr,
                       const int* __restrict__ start, const unsigned long long* __restrict__ packed,
                       const float* __restrict__ dinv, const float* __restrict__ b2,
                       float* __restrict__ out) {
    int c = (blockIdx.x * blockDim.x + threadIdx.x) >> 6;
    int lane = threadIdx.x & 63;
    if (c >= N_NODES) return;
    int eg = lane >> 3, cl = lane & 7;
    float di = dinv[c];
    float acc[8];
#pragma unroll
    for (int j = 0; j < 8; j++) acc[j] = 0.f;
    if (eg == 0 && cl < 5) {
        bf8 v = *(const bf8*)(h2 + (long)c * C_DIM + cl * 8);
#pragma unroll
        for (int j = 0; j < 8; j++) acc[j] += bf2f((unsigned short)v[j]);
    }
    int s = start[c], n = (int)(packed[c] >> 40);
    int i = eg;
    for (; i + 8 < n; i += 16) {
        int2 p0 = csr[s + i];
        int2 p1 = csr[s + i + 8];
        if (cl < 5) {
            bf8 v0 = *(const bf8*)(h2 + (long)p0.x * C_DIM + cl * 8);
            bf8 v1 = *(const bf8*)(h2 + (long)p1.x * C_DIM + cl * 8);
            float w0 = __int_as_float(p0.y), w1 = __int_as_float(p1.y);
#pragma unroll
            for (int j = 0; j < 8; j++)
                acc[j] += w0 * bf2f((unsigned short)v0[j]) + w1 * bf2f((unsigned short)v1[j]);
        }
    }
    for (; i < n; i += 8) {
        int2 p = csr[s + i];
        if (cl < 5) {
            bf8 v = *(const bf8*)(h2 + (long)p.x * C_DIM + cl * 8);
            float w = __int_as_float(p.y);
#pragma unroll
            for (int j = 0; j < 8; j++) acc[j] += w * bf2f((unsigned short)v[j]);
        }
    }
#pragma unroll
    for (int j = 0; j < 8; j++) {
        acc[j] += __shfl_xor(acc[j], 8);
        acc[j] += __shfl_xor(acc[j], 16);
        acc[j] += __shfl_xor(acc[j], 32);
    }
    float v[8];
    float lm = -INFINITY;
    if (cl < 5) {
#pragma unroll
        for (int j = 0; j < 8; j++) {
            v[j] = di * acc[j] + b2[cl * 8 + j];
            lm = fmaxf(lm, v[j]);
        }
    }
    lm = fmaxf(lm, __shfl_xor(lm, 1));
    lm = fmaxf(lm, __shfl_xor(lm, 2));
    lm = fmaxf(lm, __shfl_xor(lm, 4));
    float ls = 0.f;
    if (cl < 5) {
#pragma unroll
        for (int j = 0; j < 8; j++) ls += __expf(v[j] - lm);
    }
    ls += __shfl_xor(ls, 1);
    ls += __shfl_xor(ls, 2);
    ls += __shfl_xor(ls, 4);
    if (eg == 0 && cl < 5) {
        float lsm = lm + logf(ls);
        f32x4 o0, o1;
#pragma unroll
        for (int j = 0; j < 4; j++) { o0[j] = v[j] - lsm; o1[j] = v[j + 4] - lsm; }
        *(f32x4*)(out + (long)c * C_DIM + cl * 8)     = o0;
        *(f32x4*)(out + (long)c * C_DIM + cl * 8 + 4) = o1;
    }
}

extern "C" void kernel_launch(void* const* d_in, const int* in_sizes, int n_in,
                              void* d_out, int out_size, void* d_ws, size_t ws_size,
                              hipStream_t stream) {
    const float* x  = (const float*)d_in[0];
    const int*   ei = (const int*)d_in[1];
    const float* ea = (const float*)d_in[2];
    const float* W1 = (const float*)d_in[3];
    const float* b1 = (const float*)d_in[4];
    const float* W2 = (const float*)d_in[5];
    const float* b2 = (const float*)d_in[6];
    const int* row = ei;
    const int* col = ei + N_EDGES;

    char* ws = (char*)d_ws;
    size_t off = 0;
    auto alloc = [&](size_t bytes) -> void* {
        void* p = ws + off;
        off = (off + bytes + 255) & ~(size_t)255;
        return p;
    };
    unsigned long long* packed = (unsigned long long*)alloc((size_t)N_NODES * 8);
    float*          dinv   = (float*)alloc((size_t)N_NODES * 4);
    int*            rank   = (int*)alloc((size_t)N_EDGES * 4);
    int*            start  = (int*)alloc((size_t)N_NODES * 4);
    int*            bsum   = (int*)alloc(512 * 4);
    int2*           csr    = (int2*)alloc((size_t)N_EDGES * 8);
    unsigned short* Wp1    = (unsigned short*)alloc(32768 * 2);
    unsigned short* Wp2    = (unsigned short*)alloc(6144 * 2);
    unsigned short* h      = (unsigned short*)alloc((size_t)N_NODES * H_DIM * 2);
    unsigned short* h1     = (unsigned short*)alloc((size_t)N_NODES * H_DIM * 2);
    unsigned short* h2     = (unsigned short*)alloc((size_t)N_NODES * C_DIM * 2);

    k_init<<<NB1, 256, 0, stream>>>(packed);
    k_count<<<N_EDGES / 256, 256, 0, stream>>>(col, ea, packed, rank);
    k_rsqrt<<<NB1, 256, 0, stream>>>(packed, dinv);
    k_scan1<<<NB1, 256, 0, stream>>>(packed, start, bsum);
    k_scan2<<<1, 512, 0, stream>>>(bsum);
    k_scan3<<<NB1, 256, 0, stream>>>(start, bsum);
    k_scatter<<<N_EDGES / 256, 256, 0, stream>>>(row, col, ea, start, rank, csr);
    k_packW1<<<128, 256, 0, stream>>>(W1, Wp1);
    k_packW2<<<24, 256, 0, stream>>>(W2, Wp2);
    k_gemm1<<<N_NODES / 16, 64, 0, stream>>>(x, Wp1, dinv, h);
    k_agg1<<<N_NODES / 4, 256, 0, stream>>>(h, csr, start, packed, dinv, b1, h1);
    k_gemm2<<<N_NODES / 16, 64, 0, stream>>>(h1, Wp2, dinv, h2);
    k_agg2<<<N_NODES / 4, 256, 0, stream>>>(h2, csr, start, packed, dinv, b2, (float*)d_out);
}

// Round 5
// 432.120 us; speedup vs baseline: 1.5060x; 1.0692x over previous
//
#include <hip/hip_runtime.h>

#define N_NODES 100000
#define N_EDGES 1600000
#define F_INPUT 256
#define H_DIM   128
#define C_DIM   40
#define NB1     ((N_NODES + 255) / 256)   // 391 scan blocks

typedef short  bf8   __attribute__((ext_vector_type(8)));
typedef float  f32x4 __attribute__((ext_vector_type(4)));
typedef float  f32x2 __attribute__((ext_vector_type(2)));
typedef unsigned short u16x8 __attribute__((ext_vector_type(8)));

static __device__ __forceinline__ unsigned short f2bf(float f) {
    union { float f; unsigned u; } v; v.f = f;
    unsigned r = v.u + 0x7FFFu + ((v.u >> 16) & 1u);
    return (unsigned short)(r >> 16);
}
static __device__ __forceinline__ float bf2f(unsigned short b) {
    union { unsigned u; float f; } v; v.u = ((unsigned)b) << 16;
    return v.f;
}
// dword holding two bf16 -> (f32 low, f32 high); 2 VALU ops, pairs feed v_pk_fma_f32
static __device__ __forceinline__ f32x2 bfpair(unsigned u) {
    union { unsigned u; float f; } lo, hi;
    lo.u = u << 16; hi.u = u & 0xFFFF0000u;
    return (f32x2){lo.f, hi.f};
}

// ---------- norm preprocessing ----------
// packed[c]: bits[24:31] = edge count into c, bits[0:23] = sum(ea) in Q16 fixed point.
// deg = 1.0 (self loop) + sum(ea); max deg < 256 so both fields fit.
__global__ void k_init(unsigned* packed) {
    int i = blockIdx.x * 256 + threadIdx.x;
    if (i < N_NODES) packed[i] = (1u << 16);
}

// ONE 32-bit random atomic per edge; old count field = edge's rank at its dest.
__global__ void k_count(const int* __restrict__ col, const float* __restrict__ ea,
                        unsigned* packed, int* __restrict__ rank) {
    int e = blockIdx.x * 256 + threadIdx.x;
    if (e < N_EDGES) {
        int c = col[e];
        unsigned q = __float2uint_rn(ea[e] * 65536.0f);   // Q16
        unsigned old = atomicAdd(packed + c, (1u << 24) | q);
        rank[e] = (int)(old >> 24);
    }
}

// block-level exclusive scan of counts + fused dinv = rsqrt(deg)
__global__ void k_scan1(const unsigned* __restrict__ packed, int* start, int* bsum,
                        float* dinv) {
    __shared__ int s[256];
    int i = blockIdx.x * 256 + threadIdx.x;
    unsigned pk = (i < N_NODES) ? packed[i] : 0;
    if (i < N_NODES) dinv[i] = rsqrtf((float)(pk & 0xFFFFFFu) * (1.0f / 65536.0f));
    int v = (int)(pk >> 24);
    s[threadIdx.x] = v; __syncthreads();
    for (int off = 1; off < 256; off <<= 1) {
        int t = (threadIdx.x >= off) ? s[threadIdx.x - off] : 0;
        __syncthreads();
        s[threadIdx.x] += t;
        __syncthreads();
    }
    if (i < N_NODES) start[i] = s[threadIdx.x] - v;   // block-local exclusive
    if (threadIdx.x == 255) bsum[blockIdx.x] = s[255];
}

__global__ void k_scan2(int* bsum) {
    __shared__ int s[512];
    int v = (threadIdx.x < NB1) ? bsum[threadIdx.x] : 0;
    s[threadIdx.x] = v; __syncthreads();
    for (int off = 1; off < 512; off <<= 1) {
        int t = (threadIdx.x >= off) ? s[threadIdx.x - off] : 0;
        __syncthreads();
        s[threadIdx.x] += t;
        __syncthreads();
    }
    if (threadIdx.x < NB1) bsum[threadIdx.x] = s[threadIdx.x] - v;  // exclusive
}

// atomic-free scatter; consumers add bsum term (scan3 eliminated).
__global__ void k_scatter(const int* __restrict__ row, const int* __restrict__ col,
                          const float* __restrict__ ea,
                          const int* __restrict__ start, const int* __restrict__ bsum,
                          const int* __restrict__ rank, int2* __restrict__ csr) {
    int e = blockIdx.x * 256 + threadIdx.x;
    if (e < N_EDGES) {
        int c = col[e];
        int pos = start[c] + bsum[c >> 8] + rank[e];
        csr[pos] = make_int2(row[e], __float_as_int(ea[e]));
    }
}

// ---------- weight packing into MFMA B-fragment layout (merged W1+W2) ----------
__global__ void k_packW(const float* __restrict__ W1, const float* __restrict__ W2,
                        unsigned short* Wp1, unsigned short* Wp2) {
    int idx = blockIdx.x * 256 + threadIdx.x;
    if (idx < 32768) {       // 8 nt * 8 ks * 64 * 8
        int j = idx & 7, lane = (idx >> 3) & 63, ks = (idx >> 9) & 7, nt = idx >> 12;
        int m = lane & 15, q = lane >> 4;
        int k = ks * 32 + q * 8 + j;
        int n = nt * 16 + m;
        Wp1[idx] = f2bf(W1[k * H_DIM + n]);
    }
    int idx2 = idx - 32768;  // 3 nt * 4 ks * 64 * 8 = 6144
    if (idx2 >= 0 && idx2 < 6144) {
        int j = idx2 & 7, lane = (idx2 >> 3) & 63, ks = (idx2 >> 9) & 3, nt = idx2 >> 11;
        int m = lane & 15, q = lane >> 4;
        int k = ks * 32 + q * 8 + j;
        int n = nt * 16 + m;
        Wp2[idx2] = (n < C_DIM) ? f2bf(W2[k * C_DIM + n]) : (unsigned short)0;
    }
}

// ---------- GEMM1: hs(bf16) = dinv * (x @ W1), per-wave 16 rows x 128 cols ----------
__global__ void k_gemm1(const float* __restrict__ x, const unsigned short* __restrict__ Wp,
                        const float* __restrict__ dinv, unsigned short* __restrict__ h) {
    int tile = blockIdx.x;
    int lane = threadIdx.x & 63;
    int m = lane & 15, q = lane >> 4;
    f32x4 acc[8];
#pragma unroll
    for (int i = 0; i < 8; i++) acc[i] = (f32x4){0.f, 0.f, 0.f, 0.f};
    const float* xr = x + (long)(tile * 16 + m) * F_INPUT + q * 8;
#pragma unroll
    for (int ks = 0; ks < 8; ks++) {
        float4 a0 = *(const float4*)(xr + ks * 32);
        float4 a1 = *(const float4*)(xr + ks * 32 + 4);
        bf8 a;
        a[0] = (short)f2bf(a0.x); a[1] = (short)f2bf(a0.y);
        a[2] = (short)f2bf(a0.z); a[3] = (short)f2bf(a0.w);
        a[4] = (short)f2bf(a1.x); a[5] = (short)f2bf(a1.y);
        a[6] = (short)f2bf(a1.z); a[7] = (short)f2bf(a1.w);
#pragma unroll
        for (int nt = 0; nt < 8; nt++) {
            bf8 b = *(const bf8*)(Wp + (((nt * 8 + ks) * 64 + lane) << 3));
            acc[nt] = __builtin_amdgcn_mfma_f32_16x16x32_bf16(a, b, acc[nt], 0, 0, 0);
        }
    }
    int orow = tile * 16 + q * 4;
    f32x4 dr = *(const f32x4*)(dinv + orow);
#pragma unroll
    for (int nt = 0; nt < 8; nt++)
#pragma unroll
        for (int r = 0; r < 4; r++)
            h[(long)(orow + r) * H_DIM + nt * 16 + m] = f2bf(acc[nt][r] * dr[r]);
}

// ---------- aggregation layer 1: wave/node, predicated 20-slot gather ----------
// n = edge count is WAVE-UNIFORM (one node per wave): 5 independent predicated
// gathers/lane cover n<=20 (97.7% of Poisson-16 nodes); rare tail loops.
__global__ void k_agg1(const unsigned short* __restrict__ h, const int2* __restrict__ csr,
                       const int* __restrict__ start, const int* __restrict__ bsum,
                       const unsigned* __restrict__ packed,
                       const float* __restrict__ dinv, const float* __restrict__ b1,
                       unsigned short* __restrict__ h1) {
    int c = (blockIdx.x * blockDim.x + threadIdx.x) >> 6;
    int lane = threadIdx.x & 63;
    if (c >= N_NODES) return;
    int eg = lane >> 4, cl = lane & 15;
    float di = dinv[c];
    int s = start[c] + bsum[c >> 8];
    int n = (int)(packed[c] >> 24);

    // slot setup: csr reads are coalesced & independent
    float w[5]; int r[5];
#pragma unroll
    for (int t = 0; t < 5; t++) {
        int i = eg + 4 * t;
        int2 p = csr[s + ((i < n) ? i : 0)];   // safe: csr not last ws alloc
        bool val = (i < n);
        r[t] = val ? p.x : c;                  // dummy = self row (cached)
        w[t] = val ? __int_as_float(p.y) : 0.f;
    }
    uint4 gv[5];
#pragma unroll
    for (int t = 0; t < 5; t++)
        gv[t] = *(const uint4*)(h + (long)r[t] * H_DIM + cl * 8);
    uint4 selfv = (eg == 0) ? *(const uint4*)(h + (long)c * H_DIM + cl * 8)
                            : (uint4){0, 0, 0, 0};

    f32x2 acc[4];
#pragma unroll
    for (int k = 0; k < 4; k++) acc[k] = (f32x2){0.f, 0.f};
    {
        unsigned sv[4] = {selfv.x, selfv.y, selfv.z, selfv.w};
        if (eg == 0)
#pragma unroll
            for (int k = 0; k < 4; k++) acc[k] += bfpair(sv[k]);
    }
#pragma unroll
    for (int t = 0; t < 5; t++) {
        unsigned vv[4] = {gv[t].x, gv[t].y, gv[t].z, gv[t].w};
        f32x2 ww = (f32x2){w[t], w[t]};
#pragma unroll
        for (int k = 0; k < 4; k++) acc[k] += ww * bfpair(vv[k]);
    }
    for (int i = 20 + eg; i < n; i += 4) {     // rare tail (n > 20)
        int2 p = csr[s + i];
        uint4 v4 = *(const uint4*)(h + (long)p.x * H_DIM + cl * 8);
        unsigned vv[4] = {v4.x, v4.y, v4.z, v4.w};
        float wt = __int_as_float(p.y);
        f32x2 ww = (f32x2){wt, wt};
#pragma unroll
        for (int k = 0; k < 4; k++) acc[k] += ww * bfpair(vv[k]);
    }
#pragma unroll
    for (int k = 0; k < 4; k++) {
        acc[k].x += __shfl_xor(acc[k].x, 16); acc[k].y += __shfl_xor(acc[k].y, 16);
        acc[k].x += __shfl_xor(acc[k].x, 32); acc[k].y += __shfl_xor(acc[k].y, 32);
    }
    if (eg == 0) {
        u16x8 o;
#pragma unroll
        for (int k = 0; k < 4; k++) {
            o[2 * k]     = f2bf(fmaxf(di * acc[k].x + b1[cl * 8 + 2 * k], 0.f));
            o[2 * k + 1] = f2bf(fmaxf(di * acc[k].y + b1[cl * 8 + 2 * k + 1], 0.f));
        }
        *(u16x8*)(h1 + (long)c * H_DIM + cl * 8) = o;
    }
}

// ---------- GEMM2: h2s(bf16) = dinv * (h1 @ W2) ----------
__global__ void k_gemm2(const unsigned short* __restrict__ h1, const unsigned short* __restrict__ Wp,
                        const float* __restrict__ dinv, unsigned short* __restrict__ h2) {
    int tile = blockIdx.x;
    int lane = threadIdx.x & 63;
    int m = lane & 15, q = lane >> 4;
    f32x4 acc[3];
#pragma unroll
    for (int i = 0; i < 3; i++) acc[i] = (f32x4){0.f, 0.f, 0.f, 0.f};
    const unsigned short* hr = h1 + (long)(tile * 16 + m) * H_DIM + q * 8;
#pragma unroll
    for (int ks = 0; ks < 4; ks++) {
        bf8 a = *(const bf8*)(hr + ks * 32);
#pragma unroll
        for (int nt = 0; nt < 3; nt++) {
            bf8 b = *(const bf8*)(Wp + (((nt * 4 + ks) * 64 + lane) << 3));
            acc[nt] = __builtin_amdgcn_mfma_f32_16x16x32_bf16(a, b, acc[nt], 0, 0, 0);
        }
    }
    int orow = tile * 16 + q * 4;
    f32x4 dr = *(const f32x4*)(dinv + orow);
#pragma unroll
    for (int nt = 0; nt < 3; nt++)
#pragma unroll
        for (int r = 0; r < 4; r++) {
            int colo = nt * 16 + m;
            if (colo < C_DIM)
                h2[(long)(orow + r) * C_DIM + colo] = f2bf(acc[nt][r] * dr[r]);
        }
}

// ---------- aggregation layer 2 + bias + log_softmax: predicated 24-slot gather ----------
__global__ void k_agg2(const unsigned short* __restrict__ h2, const int2* __restrict__ csr,
                       const int* __restrict__ start, const int* __restrict__ bsum,
                       const unsigned* __restrict__ packed,
                       const float* __restrict__ dinv, const float* __restrict__ b2,
                       float* __restrict__ out) {
    int c = (blockIdx.x * blockDim.x + threadIdx.x) >> 6;
    int lane = threadIdx.x & 63;
    if (c >= N_NODES) return;
    int eg = lane >> 3, cl = lane & 7;
    float di = dinv[c];
    int s = start[c] + bsum[c >> 8];
    int n = (int)(packed[c] >> 24);

    float w[3]; int r[3];
#pragma unroll
    for (int t = 0; t < 3; t++) {
        int i = eg + 8 * t;
        int2 p = csr[s + ((i < n) ? i : 0)];
        bool val = (i < n);
        r[t] = val ? p.x : c;
        w[t] = val ? __int_as_float(p.y) : 0.f;
    }
    uint4 gv[3] = {{0,0,0,0},{0,0,0,0},{0,0,0,0}};
    uint4 selfv = {0, 0, 0, 0};
    if (cl < 5) {
#pragma unroll
        for (int t = 0; t < 3; t++)
            gv[t] = *(const uint4*)(h2 + (long)r[t] * C_DIM + cl * 8);
        if (eg == 0) selfv = *(const uint4*)(h2 + (long)c * C_DIM + cl * 8);
    }
    f32x2 acc[4];
#pragma unroll
    for (int k = 0; k < 4; k++) acc[k] = (f32x2){0.f, 0.f};
    {
        unsigned sv[4] = {selfv.x, selfv.y, selfv.z, selfv.w};
        if (eg == 0 && cl < 5)
#pragma unroll
            for (int k = 0; k < 4; k++) acc[k] += bfpair(sv[k]);
    }
#pragma unroll
    for (int t = 0; t < 3; t++) {
        unsigned vv[4] = {gv[t].x, gv[t].y, gv[t].z, gv[t].w};
        f32x2 ww = (f32x2){w[t], w[t]};
#pragma unroll
        for (int k = 0; k < 4; k++) acc[k] += ww * bfpair(vv[k]);
    }
    for (int i = 24 + eg; i < n; i += 8) {     // rare tail (n > 24)
        int2 p = csr[s + i];
        if (cl < 5) {
            uint4 v4 = *(const uint4*)(h2 + (long)p.x * C_DIM + cl * 8);
            unsigned vv[4] = {v4.x, v4.y, v4.z, v4.w};
            float wt = __int_as_float(p.y);
            f32x2 ww = (f32x2){wt, wt};
#pragma unroll
            for (int k = 0; k < 4; k++) acc[k] += ww * bfpair(vv[k]);
        }
    }
#pragma unroll
    for (int k = 0; k < 4; k++) {
        acc[k].x += __shfl_xor(acc[k].x, 8);  acc[k].y += __shfl_xor(acc[k].y, 8);
        acc[k].x += __shfl_xor(acc[k].x, 16); acc[k].y += __shfl_xor(acc[k].y, 16);
        acc[k].x += __shfl_xor(acc[k].x, 32); acc[k].y += __shfl_xor(acc[k].y, 32);
    }
    float v[8];
    float lm = -INFINITY;
    if (cl < 5) {
#pragma unroll
        for (int k = 0; k < 4; k++) {
            v[2 * k]     = di * acc[k].x + b2[cl * 8 + 2 * k];
            v[2 * k + 1] = di * acc[k].y + b2[cl * 8 + 2 * k + 1];
            lm = fmaxf(lm, fmaxf(v[2 * k], v[2 * k + 1]));
        }
    }
    lm = fmaxf(lm, __shfl_xor(lm, 1));
    lm = fmaxf(lm, __shfl_xor(lm, 2));
    lm = fmaxf(lm, __shfl_xor(lm, 4));
    float ls = 0.f;
    if (cl < 5) {
#pragma unroll
        for (int j = 0; j < 8; j++) ls += __expf(v[j] - lm);
    }
    ls += __shfl_xor(ls, 1);
    ls += __shfl_xor(ls, 2);
    ls += __shfl_xor(ls, 4);
    if (eg == 0 && cl < 5) {
        float lsm = lm + logf(ls);
        f32x4 o0, o1;
#pragma unroll
        for (int j = 0; j < 4; j++) { o0[j] = v[j] - lsm; o1[j] = v[j + 4] - lsm; }
        *(f32x4*)(out + (long)c * C_DIM + cl * 8)     = o0;
        *(f32x4*)(out + (long)c * C_DIM + cl * 8 + 4) = o1;
    }
}

extern "C" void kernel_launch(void* const* d_in, const int* in_sizes, int n_in,
                              void* d_out, int out_size, void* d_ws, size_t ws_size,
                              hipStream_t stream) {
    const float* x  = (const float*)d_in[0];
    const int*   ei = (const int*)d_in[1];
    const float* ea = (const float*)d_in[2];
    const float* W1 = (const float*)d_in[3];
    const float* b1 = (const float*)d_in[4];
    const float* W2 = (const float*)d_in[5];
    const float* b2 = (const float*)d_in[6];
    const int* row = ei;
    const int* col = ei + N_EDGES;

    char* ws = (char*)d_ws;
    size_t off = 0;
    auto alloc = [&](size_t bytes) -> void* {
        void* p = ws + off;
        off = (off + bytes + 255) & ~(size_t)255;
        return p;
    };
    unsigned*       packed = (unsigned*)alloc((size_t)N_NODES * 4);
    float*          dinv   = (float*)alloc((size_t)N_NODES * 4);
    int*            rank   = (int*)alloc((size_t)N_EDGES * 4);
    int*            start  = (int*)alloc((size_t)N_NODES * 4);
    int*            bsum   = (int*)alloc(512 * 4);
    int2*           csr    = (int2*)alloc((size_t)N_EDGES * 8);   // NOT last: OOB-safe slot reads
    unsigned short* Wp1    = (unsigned short*)alloc(32768 * 2);
    unsigned short* Wp2    = (unsigned short*)alloc(6144 * 2);
    unsigned short* h      = (unsigned short*)alloc((size_t)N_NODES * H_DIM * 2);
    unsigned short* h1     = (unsigned short*)alloc((size_t)N_NODES * H_DIM * 2);
    unsigned short* h2     = (unsigned short*)alloc((size_t)(N_NODES + 16) * C_DIM * 2);

    k_init<<<NB1, 256, 0, stream>>>(packed);
    k_count<<<N_EDGES / 256, 256, 0, stream>>>(col, ea, packed, rank);
    k_scan1<<<NB1, 256, 0, stream>>>(packed, start, bsum, dinv);
    k_scan2<<<1, 512, 0, stream>>>(bsum);
    k_scatter<<<N_EDGES / 256, 256, 0, stream>>>(row, col, ea, start, bsum, rank, csr);
    k_packW<<<153, 256, 0, stream>>>(W1, W2, Wp1, Wp2);
    k_gemm1<<<N_NODES / 16, 64, 0, stream>>>(x, Wp1, dinv, h);
    k_agg1<<<N_NODES / 4, 256, 0, stream>>>(h, csr, start, bsum, packed, dinv, b1, h1);
    k_gemm2<<<N_NODES / 16, 64, 0, stream>>>(h1, Wp2, dinv, h2);
    k_agg2<<<N_NODES / 4, 256, 0, stream>>>(h2, csr, start, bsum, packed, dinv, b2, (float*)d_out);
}

// Round 6
// 431.612 us; speedup vs baseline: 1.5078x; 1.0012x over previous
//
#include <hip/hip_runtime.h>

#define N_NODES 100000
#define N_EDGES 1600000
#define F_INPUT 256
#define H_DIM   128
#define C_DIM   40
#define NB1     ((N_NODES + 255) / 256)   // 391 scan blocks

typedef short  bf8   __attribute__((ext_vector_type(8)));
typedef float  f32x4 __attribute__((ext_vector_type(4)));
typedef float  f32x2 __attribute__((ext_vector_type(2)));
typedef unsigned short u16x8 __attribute__((ext_vector_type(8)));

static __device__ __forceinline__ unsigned short f2bf(float f) {
    union { float f; unsigned u; } v; v.f = f;
    unsigned r = v.u + 0x7FFFu + ((v.u >> 16) & 1u);
    return (unsigned short)(r >> 16);
}
static __device__ __forceinline__ float bf2f(unsigned short b) {
    union { unsigned u; float f; } v; v.u = ((unsigned)b) << 16;
    return v.f;
}
// dword holding two bf16 -> (f32 low, f32 high)
static __device__ __forceinline__ f32x2 bfpair(unsigned u) {
    union { unsigned u; float f; } lo, hi;
    lo.u = u << 16; hi.u = u & 0xFFFF0000u;
    return (f32x2){lo.f, hi.f};
}

// ---------- norm preprocessing ----------
// packed[c]: bits[24:31] = edge count, bits[0:23] = sum(ea) Q16.
__global__ void k_init(unsigned* packed) {
    int i = blockIdx.x * 256 + threadIdx.x;
    if (i < N_NODES) packed[i] = (1u << 16);
}

__global__ void k_count(const int* __restrict__ col, const float* __restrict__ ea,
                        unsigned* packed, int* __restrict__ rank) {
    int e = blockIdx.x * 256 + threadIdx.x;
    if (e < N_EDGES) {
        int c = col[e];
        unsigned q = __float2uint_rn(ea[e] * 65536.0f);   // Q16
        unsigned old = atomicAdd(packed + c, (1u << 24) | q);
        rank[e] = (int)(old >> 24);
    }
}

__global__ void k_scan1(const unsigned* __restrict__ packed, int* start, int* bsum,
                        float* dinv) {
    __shared__ int s[256];
    int i = blockIdx.x * 256 + threadIdx.x;
    unsigned pk = (i < N_NODES) ? packed[i] : 0;
    if (i < N_NODES) dinv[i] = rsqrtf((float)(pk & 0xFFFFFFu) * (1.0f / 65536.0f));
    int v = (int)(pk >> 24);
    s[threadIdx.x] = v; __syncthreads();
    for (int off = 1; off < 256; off <<= 1) {
        int t = (threadIdx.x >= off) ? s[threadIdx.x - off] : 0;
        __syncthreads();
        s[threadIdx.x] += t;
        __syncthreads();
    }
    if (i < N_NODES) start[i] = s[threadIdx.x] - v;
    if (threadIdx.x == 255) bsum[blockIdx.x] = s[255];
}

__global__ void k_scan2(int* bsum) {
    __shared__ int s[512];
    int v = (threadIdx.x < NB1) ? bsum[threadIdx.x] : 0;
    s[threadIdx.x] = v; __syncthreads();
    for (int off = 1; off < 512; off <<= 1) {
        int t = (threadIdx.x >= off) ? s[threadIdx.x - off] : 0;
        __syncthreads();
        s[threadIdx.x] += t;
        __syncthreads();
    }
    if (threadIdx.x < NB1) bsum[threadIdx.x] = s[threadIdx.x] - v;
}

__global__ void k_scatter(const int* __restrict__ row, const int* __restrict__ col,
                          const float* __restrict__ ea,
                          const int* __restrict__ start, const int* __restrict__ bsum,
                          const int* __restrict__ rank, int2* __restrict__ csr) {
    int e = blockIdx.x * 256 + threadIdx.x;
    if (e < N_EDGES) {
        int c = col[e];
        int pos = start[c] + bsum[c >> 8] + rank[e];
        csr[pos] = make_int2(row[e], __float_as_int(ea[e]));
    }
}

// ---------- weight packing into MFMA B-fragment layout (merged W1+W2) ----------
__global__ void k_packW(const float* __restrict__ W1, const float* __restrict__ W2,
                        unsigned short* Wp1, unsigned short* Wp2) {
    int idx = blockIdx.x * 256 + threadIdx.x;
    if (idx < 32768) {
        int j = idx & 7, lane = (idx >> 3) & 63, ks = (idx >> 9) & 7, nt = idx >> 12;
        int m = lane & 15, q = lane >> 4;
        int k = ks * 32 + q * 8 + j;
        int n = nt * 16 + m;
        Wp1[idx] = f2bf(W1[k * H_DIM + n]);
    }
    int idx2 = idx - 32768;
    if (idx2 >= 0 && idx2 < 6144) {
        int j = idx2 & 7, lane = (idx2 >> 3) & 63, ks = (idx2 >> 9) & 3, nt = idx2 >> 11;
        int m = lane & 15, q = lane >> 4;
        int k = ks * 32 + q * 8 + j;
        int n = nt * 16 + m;
        Wp2[idx2] = (n < C_DIM) ? f2bf(W2[k * C_DIM + n]) : (unsigned short)0;
    }
}

// ---------- GEMM1: hs(bf16) = dinv * (x @ W1) ----------
// 256 threads = 4 waves, 64 rows/block; LDS store-transpose -> coalesced 16B/lane stores.
__global__ __launch_bounds__(256, 4) void k_gemm1(const float* __restrict__ x,
                        const unsigned short* __restrict__ Wp,
                        const float* __restrict__ dinv, unsigned short* __restrict__ h) {
    __shared__ unsigned short lds_out[64 * H_DIM];   // 16 KB = the block's linear h region
    int tid = threadIdx.x;
    int wave = tid >> 6, lane = tid & 63;
    int m = lane & 15, q = lane >> 4;
    int row0 = blockIdx.x * 64 + wave * 16;
    int rowA = row0 + m; if (rowA >= N_NODES) rowA = N_NODES - 1;

    f32x4 acc[8];
#pragma unroll
    for (int i = 0; i < 8; i++) acc[i] = (f32x4){0.f, 0.f, 0.f, 0.f};
    const float* xr = x + (long)rowA * F_INPUT + q * 8;
#pragma unroll
    for (int ks = 0; ks < 8; ks++) {
        float4 a0 = *(const float4*)(xr + ks * 32);
        float4 a1 = *(const float4*)(xr + ks * 32 + 4);
        bf8 a;
        a[0] = (short)f2bf(a0.x); a[1] = (short)f2bf(a0.y);
        a[2] = (short)f2bf(a0.z); a[3] = (short)f2bf(a0.w);
        a[4] = (short)f2bf(a1.x); a[5] = (short)f2bf(a1.y);
        a[6] = (short)f2bf(a1.z); a[7] = (short)f2bf(a1.w);
#pragma unroll
        for (int nt = 0; nt < 8; nt++) {
            bf8 b = *(const bf8*)(Wp + (((nt * 8 + ks) * 64 + lane) << 3));
            acc[nt] = __builtin_amdgcn_mfma_f32_16x16x32_bf16(a, b, acc[nt], 0, 0, 0);
        }
    }
    int orow = row0 + q * 4;                          // rows orow..orow+3 (multiple of 4)
    f32x4 dr;
    if (orow + 3 < N_NODES) dr = *(const f32x4*)(dinv + orow);
    else {
#pragma unroll
        for (int r = 0; r < 4; r++) {
            int rr = orow + r; if (rr >= N_NODES) rr = N_NODES - 1;
            dr[r] = dinv[rr];
        }
    }
    int lrow = wave * 16 + q * 4;
#pragma unroll
    for (int nt = 0; nt < 8; nt++)
#pragma unroll
        for (int r = 0; r < 4; r++)
            lds_out[(lrow + r) * H_DIM + nt * 16 + m] = f2bf(acc[nt][r] * dr[r]);
    __syncthreads();
    int valid = N_NODES - blockIdx.x * 64; if (valid > 64) valid = 64;
    unsigned short* gbase = h + (size_t)blockIdx.x * 64 * H_DIM;
#pragma unroll
    for (int i = 0; i < 4; i++) {
        int idx = (i * 256 + tid) * 8;                // ushort index, 16 B chunks
        if (idx < valid * H_DIM)
            *(u16x8*)(gbase + idx) = *(const u16x8*)(lds_out + idx);
    }
}

// ---------- aggregation layer 1: wave/node, predicated 20-slot gather ----------
__global__ void k_agg1(const unsigned short* __restrict__ h, const int2* __restrict__ csr,
                       const int* __restrict__ start, const int* __restrict__ bsum,
                       const unsigned* __restrict__ packed,
                       const float* __restrict__ dinv, const float* __restrict__ b1,
                       unsigned short* __restrict__ h1) {
    int c = (blockIdx.x * blockDim.x + threadIdx.x) >> 6;
    int lane = threadIdx.x & 63;
    if (c >= N_NODES) return;
    int eg = lane >> 4, cl = lane & 15;
    float di = dinv[c];
    int s = start[c] + bsum[c >> 8];
    int n = (int)(packed[c] >> 24);

    float w[5]; int r[5];
#pragma unroll
    for (int t = 0; t < 5; t++) {
        int i = eg + 4 * t;
        int2 p = csr[s + ((i < n) ? i : 0)];
        bool val = (i < n);
        r[t] = val ? p.x : c;
        w[t] = val ? __int_as_float(p.y) : 0.f;
    }
    uint4 gv[5];
#pragma unroll
    for (int t = 0; t < 5; t++)
        gv[t] = *(const uint4*)(h + (long)r[t] * H_DIM + cl * 8);
    uint4 selfv = (eg == 0) ? *(const uint4*)(h + (long)c * H_DIM + cl * 8)
                            : (uint4){0, 0, 0, 0};

    f32x2 acc[4];
#pragma unroll
    for (int k = 0; k < 4; k++) acc[k] = (f32x2){0.f, 0.f};
    {
        unsigned sv[4] = {selfv.x, selfv.y, selfv.z, selfv.w};
        if (eg == 0)
#pragma unroll
            for (int k = 0; k < 4; k++) acc[k] += bfpair(sv[k]);
    }
#pragma unroll
    for (int t = 0; t < 5; t++) {
        unsigned vv[4] = {gv[t].x, gv[t].y, gv[t].z, gv[t].w};
        f32x2 ww = (f32x2){w[t], w[t]};
#pragma unroll
        for (int k = 0; k < 4; k++) acc[k] += ww * bfpair(vv[k]);
    }
    for (int i = 20 + eg; i < n; i += 4) {
        int2 p = csr[s + i];
        uint4 v4 = *(const uint4*)(h + (long)p.x * H_DIM + cl * 8);
        unsigned vv[4] = {v4.x, v4.y, v4.z, v4.w};
        float wt = __int_as_float(p.y);
        f32x2 ww = (f32x2){wt, wt};
#pragma unroll
        for (int k = 0; k < 4; k++) acc[k] += ww * bfpair(vv[k]);
    }
#pragma unroll
    for (int k = 0; k < 4; k++) {
        acc[k].x += __shfl_xor(acc[k].x, 16); acc[k].y += __shfl_xor(acc[k].y, 16);
        acc[k].x += __shfl_xor(acc[k].x, 32); acc[k].y += __shfl_xor(acc[k].y, 32);
    }
    if (eg == 0) {
        u16x8 o;
#pragma unroll
        for (int k = 0; k < 4; k++) {
            o[2 * k]     = f2bf(fmaxf(di * acc[k].x + b1[cl * 8 + 2 * k], 0.f));
            o[2 * k + 1] = f2bf(fmaxf(di * acc[k].y + b1[cl * 8 + 2 * k + 1], 0.f));
        }
        *(u16x8*)(h1 + (long)c * H_DIM + cl * 8) = o;
    }
}

// ---------- GEMM2: h2s(bf16) = dinv * (h1 @ W2), LDS store-transpose ----------
__global__ __launch_bounds__(256, 4) void k_gemm2(const unsigned short* __restrict__ h1,
                        const unsigned short* __restrict__ Wp,
                        const float* __restrict__ dinv, unsigned short* __restrict__ h2) {
    __shared__ unsigned short lds_out[64 * C_DIM];   // 5120 B = block's linear h2 region
    int tid = threadIdx.x;
    int wave = tid >> 6, lane = tid & 63;
    int m = lane & 15, q = lane >> 4;
    int row0 = blockIdx.x * 64 + wave * 16;
    int rowA = row0 + m; if (rowA >= N_NODES) rowA = N_NODES - 1;

    f32x4 acc[3];
#pragma unroll
    for (int i = 0; i < 3; i++) acc[i] = (f32x4){0.f, 0.f, 0.f, 0.f};
    const unsigned short* hr = h1 + (long)rowA * H_DIM + q * 8;
#pragma unroll
    for (int ks = 0; ks < 4; ks++) {
        bf8 a = *(const bf8*)(hr + ks * 32);
#pragma unroll
        for (int nt = 0; nt < 3; nt++) {
            bf8 b = *(const bf8*)(Wp + (((nt * 4 + ks) * 64 + lane) << 3));
            acc[nt] = __builtin_amdgcn_mfma_f32_16x16x32_bf16(a, b, acc[nt], 0, 0, 0);
        }
    }
    int orow = row0 + q * 4;
    f32x4 dr;
    if (orow + 3 < N_NODES) dr = *(const f32x4*)(dinv + orow);
    else {
#pragma unroll
        for (int r = 0; r < 4; r++) {
            int rr = orow + r; if (rr >= N_NODES) rr = N_NODES - 1;
            dr[r] = dinv[rr];
        }
    }
    int lrow = wave * 16 + q * 4;
#pragma unroll
    for (int nt = 0; nt < 3; nt++)
#pragma unroll
        for (int r = 0; r < 4; r++) {
            int colo = nt * 16 + m;
            if (colo < C_DIM)
                lds_out[(lrow + r) * C_DIM + colo] = f2bf(acc[nt][r] * dr[r]);
        }
    __syncthreads();
    int valid = N_NODES - blockIdx.x * 64; if (valid > 64) valid = 64;
    unsigned short* gbase = h2 + (size_t)blockIdx.x * 64 * C_DIM;
    int total = valid * C_DIM;                        // <= 2560 ushorts
#pragma unroll
    for (int i = 0; i < 3; i++) {
        int idx = (i * 256 + tid) * 4;                // 8 B chunks
        if (idx < total)
            *(uint2*)(gbase + idx) = *(const uint2*)(lds_out + idx);
    }
}

// ---------- aggregation layer 2 + bias + log_softmax: predicated 24-slot gather ----------
__global__ void k_agg2(const unsigned short* __restrict__ h2, const int2* __restrict__ csr,
                       const int* __restrict__ start, const int* __restrict__ bsum,
                       const unsigned* __restrict__ packed,
                       const float* __restrict__ dinv, const float* __restrict__ b2,
                       float* __restrict__ out) {
    int c = (blockIdx.x * blockDim.x + threadIdx.x) >> 6;
    int lane = threadIdx.x & 63;
    if (c >= N_NODES) return;
    int eg = lane >> 3, cl = lane & 7;
    float di = dinv[c];
    int s = start[c] + bsum[c >> 8];
    int n = (int)(packed[c] >> 24);

    float w[3]; int r[3];
#pragma unroll
    for (int t = 0; t < 3; t++) {
        int i = eg + 8 * t;
        int2 p = csr[s + ((i < n) ? i : 0)];
        bool val = (i < n);
        r[t] = val ? p.x : c;
        w[t] = val ? __int_as_float(p.y) : 0.f;
    }
    uint4 gv[3] = {{0,0,0,0},{0,0,0,0},{0,0,0,0}};
    uint4 selfv = {0, 0, 0, 0};
    if (cl < 5) {
#pragma unroll
        for (int t = 0; t < 3; t++)
            gv[t] = *(const uint4*)(h2 + (long)r[t] * C_DIM + cl * 8);
        if (eg == 0) selfv = *(const uint4*)(h2 + (long)c * C_DIM + cl * 8);
    }
    f32x2 acc[4];
#pragma unroll
    for (int k = 0; k < 4; k++) acc[k] = (f32x2){0.f, 0.f};
    {
        unsigned sv[4] = {selfv.x, selfv.y, selfv.z, selfv.w};
        if (eg == 0 && cl < 5)
#pragma unroll
            for (int k = 0; k < 4; k++) acc[k] += bfpair(sv[k]);
    }
#pragma unroll
    for (int t = 0; t < 3; t++) {
        unsigned vv[4] = {gv[t].x, gv[t].y, gv[t].z, gv[t].w};
        f32x2 ww = (f32x2){w[t], w[t]};
#pragma unroll
        for (int k = 0; k < 4; k++) acc[k] += ww * bfpair(vv[k]);
    }
    for (int i = 24 + eg; i < n; i += 8) {
        int2 p = csr[s + i];
        if (cl < 5) {
            uint4 v4 = *(const uint4*)(h2 + (long)p.x * C_DIM + cl * 8);
            unsigned vv[4] = {v4.x, v4.y, v4.z, v4.w};
            float wt = __int_as_float(p.y);
            f32x2 ww = (f32x2){wt, wt};
#pragma unroll
            for (int k = 0; k < 4; k++) acc[k] += ww * bfpair(vv[k]);
        }
    }
#pragma unroll
    for (int k = 0; k < 4; k++) {
        acc[k].x += __shfl_xor(acc[k].x, 8);  acc[k].y += __shfl_xor(acc[k].y, 8);
        acc[k].x += __shfl_xor(acc[k].x, 16); acc[k].y += __shfl_xor(acc[k].y, 16);
        acc[k].x += __shfl_xor(acc[k].x, 32); acc[k].y += __shfl_xor(acc[k].y, 32);
    }
    float v[8];
    float lm = -INFINITY;
    if (cl < 5) {
#pragma unroll
        for (int k = 0; k < 4; k++) {
            v[2 * k]     = di * acc[k].x + b2[cl * 8 + 2 * k];
            v[2 * k + 1] = di * acc[k].y + b2[cl * 8 + 2 * k + 1];
            lm = fmaxf(lm, fmaxf(v[2 * k], v[2 * k + 1]));
        }
    }
    lm = fmaxf(lm, __shfl_xor(lm, 1));
    lm = fmaxf(lm, __shfl_xor(lm, 2));
    lm = fmaxf(lm, __shfl_xor(lm, 4));
    float ls = 0.f;
    if (cl < 5) {
#pragma unroll
        for (int j = 0; j < 8; j++) ls += __expf(v[j] - lm);
    }
    ls += __shfl_xor(ls, 1);
    ls += __shfl_xor(ls, 2);
    ls += __shfl_xor(ls, 4);
    if (eg == 0 && cl < 5) {
        float lsm = lm + logf(ls);
        f32x4 o0, o1;
#pragma unroll
        for (int j = 0; j < 4; j++) { o0[j] = v[j] - lsm; o1[j] = v[j + 4] - lsm; }
        *(f32x4*)(out + (long)c * C_DIM + cl * 8)     = o0;
        *(f32x4*)(out + (long)c * C_DIM + cl * 8 + 4) = o1;
    }
}

extern "C" void kernel_launch(void* const* d_in, const int* in_sizes, int n_in,
                              void* d_out, int out_size, void* d_ws, size_t ws_size,
                              hipStream_t stream) {
    const float* x  = (const float*)d_in[0];
    const int*   ei = (const int*)d_in[1];
    const float* ea = (const float*)d_in[2];
    const float* W1 = (const float*)d_in[3];
    const float* b1 = (const float*)d_in[4];
    const float* W2 = (const float*)d_in[5];
    const float* b2 = (const float*)d_in[6];
    const int* row = ei;
    const int* col = ei + N_EDGES;

    char* ws = (char*)d_ws;
    size_t off = 0;
    auto alloc = [&](size_t bytes) -> void* {
        void* p = ws + off;
        off = (off + bytes + 255) & ~(size_t)255;
        return p;
    };
    unsigned*       packed = (unsigned*)alloc((size_t)N_NODES * 4);
    float*          dinv   = (float*)alloc((size_t)N_NODES * 4);
    int*            rank   = (int*)alloc((size_t)N_EDGES * 4);
    int*            start  = (int*)alloc((size_t)N_NODES * 4);
    int*            bsum   = (int*)alloc(512 * 4);
    int2*           csr    = (int2*)alloc((size_t)N_EDGES * 8);   // NOT last: OOB-safe slot reads
    unsigned short* Wp1    = (unsigned short*)alloc(32768 * 2);
    unsigned short* Wp2    = (unsigned short*)alloc(6144 * 2);
    unsigned short* h      = (unsigned short*)alloc((size_t)(N_NODES + 64) * H_DIM * 2);
    unsigned short* h1     = (unsigned short*)alloc((size_t)N_NODES * H_DIM * 2);
    unsigned short* h2     = (unsigned short*)alloc((size_t)(N_NODES + 64) * C_DIM * 2);

    k_init<<<NB1, 256, 0, stream>>>(packed);
    k_count<<<N_EDGES / 256, 256, 0, stream>>>(col, ea, packed, rank);
    k_scan1<<<NB1, 256, 0, stream>>>(packed, start, bsum, dinv);
    k_scan2<<<1, 512, 0, stream>>>(bsum);
    k_scatter<<<N_EDGES / 256, 256, 0, stream>>>(row, col, ea, start, bsum, rank, csr);
    k_packW<<<153, 256, 0, stream>>>(W1, W2, Wp1, Wp2);
    k_gemm1<<<(N_NODES + 63) / 64, 256, 0, stream>>>(x, Wp1, dinv, h);
    k_agg1<<<N_NODES / 4, 256, 0, stream>>>(h, csr, start, bsum, packed, dinv, b1, h1);
    k_gemm2<<<(N_NODES + 63) / 64, 256, 0, stream>>>(h1, Wp2, dinv, h2);
    k_agg2<<<N_NODES / 4, 256, 0, stream>>>(h2, csr, start, bsum, packed, dinv, b2, (float*)d_out);
}

// Round 7
// 403.548 us; speedup vs baseline: 1.6127x; 1.0695x over previous
//
#include <hip/hip_runtime.h>

#define N_NODES 100000
#define N_EDGES 1600000
#define F_INPUT 256
#define H_DIM   128
#define C_DIM   40
#define NB1     ((N_NODES + 255) / 256)   // 391 scan blocks
#define NGEMM1  1563                      // 64-row tiles covering 100032 rows
#define NCOUNT  6250                      // 256-edge chunks
#define NMEGA   (NGEMM1 + NCOUNT)         // 7813

typedef short  bf8   __attribute__((ext_vector_type(8)));
typedef float  f32x4 __attribute__((ext_vector_type(4)));
typedef float  f32x2 __attribute__((ext_vector_type(2)));
typedef unsigned short u16x8 __attribute__((ext_vector_type(8)));

static __device__ __forceinline__ unsigned short f2bf(float f) {
    union { float f; unsigned u; } v; v.f = f;
    unsigned r = v.u + 0x7FFFu + ((v.u >> 16) & 1u);
    return (unsigned short)(r >> 16);
}
static __device__ __forceinline__ float bf2f(unsigned short b) {
    union { unsigned u; float f; } v; v.u = ((unsigned)b) << 16;
    return v.f;
}
static __device__ __forceinline__ f32x2 bfpair(unsigned u) {
    union { unsigned u; float f; } lo, hi;
    lo.u = u << 16; hi.u = u & 0xFFFF0000u;
    return (f32x2){lo.f, hi.f};
}

// ---------- k_pre: init packed  ∪  pack W1/W2 into MFMA B-frag layout ----------
__global__ void k_pre(unsigned* packed, const float* __restrict__ W1,
                      const float* __restrict__ W2,
                      unsigned short* Wp1, unsigned short* Wp2) {
    if (blockIdx.x < NB1) {
        int i = blockIdx.x * 256 + threadIdx.x;
        if (i < N_NODES) packed[i] = (1u << 16);   // deg starts at 1.0 (self loop), Q16
        return;
    }
    int idx = (blockIdx.x - NB1) * 256 + threadIdx.x;
    if (idx < 32768) {       // 8 nt * 8 ks * 64 * 8
        int j = idx & 7, lane = (idx >> 3) & 63, ks = (idx >> 9) & 7, nt = idx >> 12;
        int m = lane & 15, q = lane >> 4;
        Wp1[idx] = f2bf(W1[(ks * 32 + q * 8 + j) * H_DIM + nt * 16 + m]);
    }
    int idx2 = idx - 32768;  // 3 nt * 4 ks * 64 * 8 = 6144
    if (idx2 >= 0 && idx2 < 6144) {
        int j = idx2 & 7, lane = (idx2 >> 3) & 63, ks = (idx2 >> 9) & 3, nt = idx2 >> 11;
        int m = lane & 15, q = lane >> 4;
        int n = nt * 16 + m;
        Wp2[idx2] = (n < C_DIM) ? f2bf(W2[(ks * 32 + q * 8 + j) * C_DIM + n]) : (unsigned short)0;
    }
}

// ---------- k_mega: GEMM1 (h = x@W1, bf16, unscaled)  ∪  edge count/degree ----------
// Independent chains co-scheduled: gemm blocks are latency-bound, count blocks
// atomic-bound -> overlap. Interleave 1:4 via blockIdx%5.
__global__ __launch_bounds__(256, 4) void k_mega(
        const float* __restrict__ x, const unsigned short* __restrict__ Wp,
        unsigned short* __restrict__ h,
        const int* __restrict__ col, const float* __restrict__ ea,
        unsigned* packed, int* __restrict__ rank) {
    __shared__ unsigned short lds_out[64 * H_DIM];
    int b = blockIdx.x;
    bool is_gemm = (b % 5 == 0);
    if (!is_gemm) {
        // ---- count role ----
        int cb = b - b / 5 - 1;                     // 0..6249
        int e = cb * 256 + threadIdx.x;
        if (e < N_EDGES) {
            int c = col[e];
            unsigned q = __float2uint_rn(ea[e] * 65536.0f);   // Q16
            unsigned old = atomicAdd(packed + c, (1u << 24) | q);
            rank[e] = (int)(old >> 24);
        }
        return;
    }
    // ---- gemm role: 64 rows per block ----
    int tile = b / 5;                               // 0..1562
    int tid = threadIdx.x;
    int wave = tid >> 6, lane = tid & 63;
    int m = lane & 15, q = lane >> 4;
    int row0 = tile * 64 + wave * 16;
    int rowA = row0 + m; if (rowA >= N_NODES) rowA = N_NODES - 1;

    f32x4 acc[8];
#pragma unroll
    for (int i = 0; i < 8; i++) acc[i] = (f32x4){0.f, 0.f, 0.f, 0.f};
    const float* xr = x + (long)rowA * F_INPUT + q * 8;
#pragma unroll
    for (int ks = 0; ks < 8; ks++) {
        float4 a0 = *(const float4*)(xr + ks * 32);
        float4 a1 = *(const float4*)(xr + ks * 32 + 4);
        bf8 a;
        a[0] = (short)f2bf(a0.x); a[1] = (short)f2bf(a0.y);
        a[2] = (short)f2bf(a0.z); a[3] = (short)f2bf(a0.w);
        a[4] = (short)f2bf(a1.x); a[5] = (short)f2bf(a1.y);
        a[6] = (short)f2bf(a1.z); a[7] = (short)f2bf(a1.w);
#pragma unroll
        for (int nt = 0; nt < 8; nt++) {
            bf8 bb = *(const bf8*)(Wp + (((nt * 8 + ks) * 64 + lane) << 3));
            acc[nt] = __builtin_amdgcn_mfma_f32_16x16x32_bf16(a, bb, acc[nt], 0, 0, 0);
        }
    }
    int lrow = wave * 16 + q * 4;
#pragma unroll
    for (int nt = 0; nt < 8; nt++)
#pragma unroll
        for (int r = 0; r < 4; r++)
            lds_out[(lrow + r) * H_DIM + nt * 16 + m] = f2bf(acc[nt][r]);
    __syncthreads();
    int valid = N_NODES - tile * 64; if (valid > 64) valid = 64;
    unsigned short* gbase = h + (size_t)tile * 64 * H_DIM;
#pragma unroll
    for (int i = 0; i < 4; i++) {
        int idx = (i * 256 + tid) * 8;
        if (idx < valid * H_DIM)
            *(u16x8*)(gbase + idx) = *(const u16x8*)(lds_out + idx);
    }
}

// ---------- scan + dinv ----------
__global__ void k_scan1(const unsigned* __restrict__ packed, int* start, int* bsum,
                        float* dinv) {
    __shared__ int s[256];
    int i = blockIdx.x * 256 + threadIdx.x;
    unsigned pk = (i < N_NODES) ? packed[i] : 0;
    if (i < N_NODES) dinv[i] = rsqrtf((float)(pk & 0xFFFFFFu) * (1.0f / 65536.0f));
    int v = (int)(pk >> 24);
    s[threadIdx.x] = v; __syncthreads();
    for (int off = 1; off < 256; off <<= 1) {
        int t = (threadIdx.x >= off) ? s[threadIdx.x - off] : 0;
        __syncthreads();
        s[threadIdx.x] += t;
        __syncthreads();
    }
    if (i < N_NODES) start[i] = s[threadIdx.x] - v;
    if (threadIdx.x == 255) bsum[blockIdx.x] = s[255];
}

__global__ void k_scan2(int* bsum) {
    __shared__ int s[512];
    int v = (threadIdx.x < NB1) ? bsum[threadIdx.x] : 0;
    s[threadIdx.x] = v; __syncthreads();
    for (int off = 1; off < 512; off <<= 1) {
        int t = (threadIdx.x >= off) ? s[threadIdx.x - off] : 0;
        __syncthreads();
        s[threadIdx.x] += t;
        __syncthreads();
    }
    if (threadIdx.x < NB1) bsum[threadIdx.x] = s[threadIdx.x] - v;
}

// atomic-free scatter; csr weight = ea * dinv[row]  (dest-side dinv applied in agg)
__global__ void k_scatter(const int* __restrict__ row, const int* __restrict__ col,
                          const float* __restrict__ ea, const float* __restrict__ dinv,
                          const int* __restrict__ start, const int* __restrict__ bsum,
                          const int* __restrict__ rank, int2* __restrict__ csr) {
    int e = blockIdx.x * 256 + threadIdx.x;
    if (e < N_EDGES) {
        int c = col[e];
        int r = row[e];
        int pos = start[c] + bsum[c >> 8] + rank[e];
        float w = ea[e] * dinv[r];
        csr[pos] = make_int2(r, __float_as_int(w));
    }
}

// ---------- aggregation layer 1: wave/node, predicated 20-slot gather ----------
// h1[c] = relu(di*(di*h[c] + sum w_e*h[row_e]) + b1),  w_e = ea*dinv[row]
__global__ void k_agg1(const unsigned short* __restrict__ h, const int2* __restrict__ csr,
                       const int* __restrict__ start, const int* __restrict__ bsum,
                       const unsigned* __restrict__ packed,
                       const float* __restrict__ dinv, const float* __restrict__ b1,
                       unsigned short* __restrict__ h1) {
    int c = (blockIdx.x * blockDim.x + threadIdx.x) >> 6;
    int lane = threadIdx.x & 63;
    if (c >= N_NODES) return;
    int eg = lane >> 4, cl = lane & 15;
    float di = dinv[c];
    int s = start[c] + bsum[c >> 8];
    int n = (int)(packed[c] >> 24);

    float w[5]; int r[5];
#pragma unroll
    for (int t = 0; t < 5; t++) {
        int i = eg + 4 * t;
        int2 p = csr[s + ((i < n) ? i : 0)];
        bool val = (i < n);
        r[t] = val ? p.x : c;
        w[t] = val ? __int_as_float(p.y) : 0.f;
    }
    uint4 gv[5];
#pragma unroll
    for (int t = 0; t < 5; t++)
        gv[t] = *(const uint4*)(h + (long)r[t] * H_DIM + cl * 8);
    uint4 selfv = (eg == 0) ? *(const uint4*)(h + (long)c * H_DIM + cl * 8)
                            : (uint4){0, 0, 0, 0};

    f32x2 acc[4];
#pragma unroll
    for (int k = 0; k < 4; k++) acc[k] = (f32x2){0.f, 0.f};
    {
        unsigned sv[4] = {selfv.x, selfv.y, selfv.z, selfv.w};
        f32x2 dd = (f32x2){di, di};
        if (eg == 0)
#pragma unroll
            for (int k = 0; k < 4; k++) acc[k] += dd * bfpair(sv[k]);
    }
#pragma unroll
    for (int t = 0; t < 5; t++) {
        unsigned vv[4] = {gv[t].x, gv[t].y, gv[t].z, gv[t].w};
        f32x2 ww = (f32x2){w[t], w[t]};
#pragma unroll
        for (int k = 0; k < 4; k++) acc[k] += ww * bfpair(vv[k]);
    }
    for (int i = 20 + eg; i < n; i += 4) {
        int2 p = csr[s + i];
        uint4 v4 = *(const uint4*)(h + (long)p.x * H_DIM + cl * 8);
        unsigned vv[4] = {v4.x, v4.y, v4.z, v4.w};
        float wt = __int_as_float(p.y);
        f32x2 ww = (f32x2){wt, wt};
#pragma unroll
        for (int k = 0; k < 4; k++) acc[k] += ww * bfpair(vv[k]);
    }
#pragma unroll
    for (int k = 0; k < 4; k++) {
        acc[k].x += __shfl_xor(acc[k].x, 16); acc[k].y += __shfl_xor(acc[k].y, 16);
        acc[k].x += __shfl_xor(acc[k].x, 32); acc[k].y += __shfl_xor(acc[k].y, 32);
    }
    if (eg == 0) {
        u16x8 o;
#pragma unroll
        for (int k = 0; k < 4; k++) {
            o[2 * k]     = f2bf(fmaxf(di * acc[k].x + b1[cl * 8 + 2 * k], 0.f));
            o[2 * k + 1] = f2bf(fmaxf(di * acc[k].y + b1[cl * 8 + 2 * k + 1], 0.f));
        }
        *(u16x8*)(h1 + (long)c * H_DIM + cl * 8) = o;
    }
}

// ---------- GEMM2: h2(bf16) = h1 @ W2 (unscaled), LDS store-transpose ----------
__global__ __launch_bounds__(256, 4) void k_gemm2(const unsigned short* __restrict__ h1,
                        const unsigned short* __restrict__ Wp,
                        unsigned short* __restrict__ h2) {
    __shared__ unsigned short lds_out[64 * C_DIM];
    int tid = threadIdx.x;
    int wave = tid >> 6, lane = tid & 63;
    int m = lane & 15, q = lane >> 4;
    int row0 = blockIdx.x * 64 + wave * 16;
    int rowA = row0 + m; if (rowA >= N_NODES) rowA = N_NODES - 1;

    f32x4 acc[3];
#pragma unroll
    for (int i = 0; i < 3; i++) acc[i] = (f32x4){0.f, 0.f, 0.f, 0.f};
    const unsigned short* hr = h1 + (long)rowA * H_DIM + q * 8;
#pragma unroll
    for (int ks = 0; ks < 4; ks++) {
        bf8 a = *(const bf8*)(hr + ks * 32);
#pragma unroll
        for (int nt = 0; nt < 3; nt++) {
            bf8 b = *(const bf8*)(Wp + (((nt * 4 + ks) * 64 + lane) << 3));
            acc[nt] = __builtin_amdgcn_mfma_f32_16x16x32_bf16(a, b, acc[nt], 0, 0, 0);
        }
    }
    int lrow = wave * 16 + q * 4;
#pragma unroll
    for (int nt = 0; nt < 3; nt++)
#pragma unroll
        for (int r = 0; r < 4; r++) {
            int colo = nt * 16 + m;
            if (colo < C_DIM)
                lds_out[(lrow + r) * C_DIM + colo] = f2bf(acc[nt][r]);
        }
    __syncthreads();
    int valid = N_NODES - blockIdx.x * 64; if (valid > 64) valid = 64;
    unsigned short* gbase = h2 + (size_t)blockIdx.x * 64 * C_DIM;
    int total = valid * C_DIM;
#pragma unroll
    for (int i = 0; i < 3; i++) {
        int idx = (i * 256 + tid) * 4;
        if (idx < total)
            *(uint2*)(gbase + idx) = *(const uint2*)(lds_out + idx);
    }
}

// ---------- aggregation layer 2 + bias + log_softmax: predicated 24-slot gather ----------
__global__ void k_agg2(const unsigned short* __restrict__ h2, const int2* __restrict__ csr,
                       const int* __restrict__ start, const int* __restrict__ bsum,
                       const unsigned* __restrict__ packed,
                       const float* __restrict__ dinv, const float* __restrict__ b2,
                       float* __restrict__ out) {
    int c = (blockIdx.x * blockDim.x + threadIdx.x) >> 6;
    int lane = threadIdx.x & 63;
    if (c >= N_NODES) return;
    int eg = lane >> 3, cl = lane & 7;
    float di = dinv[c];
    int s = start[c] + bsum[c >> 8];
    int n = (int)(packed[c] >> 24);

    float w[3]; int r[3];
#pragma unroll
    for (int t = 0; t < 3; t++) {
        int i = eg + 8 * t;
        int2 p = csr[s + ((i < n) ? i : 0)];
        bool val = (i < n);
        r[t] = val ? p.x : c;
        w[t] = val ? __int_as_float(p.y) : 0.f;
    }
    uint4 gv[3] = {{0,0,0,0},{0,0,0,0},{0,0,0,0}};
    uint4 selfv = {0, 0, 0, 0};
    if (cl < 5) {
#pragma unroll
        for (int t = 0; t < 3; t++)
            gv[t] = *(const uint4*)(h2 + (long)r[t] * C_DIM + cl * 8);
        if (eg == 0) selfv = *(const uint4*)(h2 + (long)c * C_DIM + cl * 8);
    }
    f32x2 acc[4];
#pragma unroll
    for (int k = 0; k < 4; k++) acc[k] = (f32x2){0.f, 0.f};
    {
        unsigned sv[4] = {selfv.x, selfv.y, selfv.z, selfv.w};
        f32x2 dd = (f32x2){di, di};
        if (eg == 0 && cl < 5)
#pragma unroll
            for (int k = 0; k < 4; k++) acc[k] += dd * bfpair(sv[k]);
    }
#pragma unroll
    for (int t = 0; t < 3; t++) {
        unsigned vv[4] = {gv[t].x, gv[t].y, gv[t].z, gv[t].w};
        f32x2 ww = (f32x2){w[t], w[t]};
#pragma unroll
        for (int k = 0; k < 4; k++) acc[k] += ww * bfpair(vv[k]);
    }
    for (int i = 24 + eg; i < n; i += 8) {
        int2 p = csr[s + i];
        if (cl < 5) {
            uint4 v4 = *(const uint4*)(h2 + (long)p.x * C_DIM + cl * 8);
            unsigned vv[4] = {v4.x, v4.y, v4.z, v4.w};
            float wt = __int_as_float(p.y);
            f32x2 ww = (f32x2){wt, wt};
#pragma unroll
            for (int k = 0; k < 4; k++) acc[k] += ww * bfpair(vv[k]);
        }
    }
#pragma unroll
    for (int k = 0; k < 4; k++) {
        acc[k].x += __shfl_xor(acc[k].x, 8);  acc[k].y += __shfl_xor(acc[k].y, 8);
        acc[k].x += __shfl_xor(acc[k].x, 16); acc[k].y += __shfl_xor(acc[k].y, 16);
        acc[k].x += __shfl_xor(acc[k].x, 32); acc[k].y += __shfl_xor(acc[k].y, 32);
    }
    float v[8];
    float lm = -INFINITY;
    if (cl < 5) {
#pragma unroll
        for (int k = 0; k < 4; k++) {
            v[2 * k]     = di * acc[k].x + b2[cl * 8 + 2 * k];
            v[2 * k + 1] = di * acc[k].y + b2[cl * 8 + 2 * k + 1];
            lm = fmaxf(lm, fmaxf(v[2 * k], v[2 * k + 1]));
        }
    }
    lm = fmaxf(lm, __shfl_xor(lm, 1));
    lm = fmaxf(lm, __shfl_xor(lm, 2));
    lm = fmaxf(lm, __shfl_xor(lm, 4));
    float ls = 0.f;
    if (cl < 5) {
#pragma unroll
        for (int j = 0; j < 8; j++) ls += __expf(v[j] - lm);
    }
    ls += __shfl_xor(ls, 1);
    ls += __shfl_xor(ls, 2);
    ls += __shfl_xor(ls, 4);
    if (eg == 0 && cl < 5) {
        float lsm = lm + logf(ls);
        f32x4 o0, o1;
#pragma unroll
        for (int j = 0; j < 4; j++) { o0[j] = v[j] - lsm; o1[j] = v[j + 4] - lsm; }
        *(f32x4*)(out + (long)c * C_DIM + cl * 8)     = o0;
        *(f32x4*)(out + (long)c * C_DIM + cl * 8 + 4) = o1;
    }
}

extern "C" void kernel_launch(void* const* d_in, const int* in_sizes, int n_in,
                              void* d_out, int out_size, void* d_ws, size_t ws_size,
                              hipStream_t stream) {
    const float* x  = (const float*)d_in[0];
    const int*   ei = (const int*)d_in[1];
    const float* ea = (const float*)d_in[2];
    const float* W1 = (const float*)d_in[3];
    const float* b1 = (const float*)d_in[4];
    const float* W2 = (const float*)d_in[5];
    const float* b2 = (const float*)d_in[6];
    const int* row = ei;
    const int* col = ei + N_EDGES;

    char* ws = (char*)d_ws;
    size_t off = 0;
    auto alloc = [&](size_t bytes) -> void* {
        void* p = ws + off;
        off = (off + bytes + 255) & ~(size_t)255;
        return p;
    };
    unsigned*       packed = (unsigned*)alloc((size_t)N_NODES * 4);
    float*          dinv   = (float*)alloc((size_t)N_NODES * 4);
    int*            rank   = (int*)alloc((size_t)N_EDGES * 4);
    int*            start  = (int*)alloc((size_t)N_NODES * 4);
    int*            bsum   = (int*)alloc(512 * 4);
    int2*           csr    = (int2*)alloc((size_t)N_EDGES * 8);   // NOT last: OOB-safe slot reads
    unsigned short* Wp1    = (unsigned short*)alloc(32768 * 2);
    unsigned short* Wp2    = (unsigned short*)alloc(6144 * 2);
    unsigned short* h      = (unsigned short*)alloc((size_t)(N_NODES + 64) * H_DIM * 2);
    unsigned short* h1     = (unsigned short*)alloc((size_t)N_NODES * H_DIM * 2);
    unsigned short* h2     = (unsigned short*)alloc((size_t)(N_NODES + 64) * C_DIM * 2);

    k_pre<<<NB1 + 152, 256, 0, stream>>>(packed, W1, W2, Wp1, Wp2);
    k_mega<<<NMEGA, 256, 0, stream>>>(x, Wp1, h, col, ea, packed, rank);
    k_scan1<<<NB1, 256, 0, stream>>>(packed, start, bsum, dinv);
    k_scan2<<<1, 512, 0, stream>>>(bsum);
    k_scatter<<<N_EDGES / 256, 256, 0, stream>>>(row, col, ea, dinv, start, bsum, rank, csr);
    k_agg1<<<N_NODES / 4, 256, 0, stream>>>(h, csr, start, bsum, packed, dinv, b1, h1);
    k_gemm2<<<(N_NODES + 63) / 64, 256, 0, stream>>>(h1, Wp2, h2);
    k_agg2<<<N_NODES / 4, 256, 0, stream>>>(h2, csr, start, bsum, packed, dinv, b2, (float*)d_out);
}